// Round 1
// baseline (67499.097 us; speedup 1.0000x reference)
//
#include <hip/hip_runtime.h>
#include <hip/hip_bf16.h>
#include <math.h>

#define T_STEPS 256
#define BATCH   64
#define DIM     1024
#define HID     1024

// ---------------------------------------------------------------------------
// xproj GEMM: XP[n][gate*1024+j] = sum_k X[n][k] * Wgate[j][k]
// M = T*B = 16384, N = 4096 (4 gates x 1024), K = 1024
// 128x128 tile, 256 threads, 8x8 per thread, K-step 16.
// ---------------------------------------------------------------------------
__global__ __launch_bounds__(256) void xproj_gemm(
    const float* __restrict__ X,
    const float* __restrict__ W0, const float* __restrict__ W1,
    const float* __restrict__ W2, const float* __restrict__ W3,
    float* __restrict__ XP)
{
    const int K = 1024;
    __shared__ float As[16][128];   // [k][m]
    __shared__ float Bs[16][128];   // [k][n_local]

    int bm = blockIdx.x;            // 0..127  (M/128)
    int bn = blockIdx.y;            // 0..31   (4096/128)
    const float* W = (bn < 8) ? W0 : (bn < 16) ? W1 : (bn < 24) ? W2 : W3;
    int jbase   = (bn * 128) & 1023;   // row base inside the selected gate weight
    int rowBase = bm * 128;

    int tid = threadIdx.x;
    int tx = tid & 15, ty = tid >> 4;

    float acc[8][8];
#pragma unroll
    for (int i = 0; i < 8; ++i)
#pragma unroll
        for (int j = 0; j < 8; ++j) acc[i][j] = 0.f;

    for (int k0 = 0; k0 < K; k0 += 16) {
#pragma unroll
        for (int i = 0; i < 2; ++i) {
            int fl = tid * 2 + i;          // 0..511
            int m  = fl >> 2;              // 0..127
            int kq = fl & 3;               // which float4 along k
            float4 a = *(const float4*)(X + (size_t)(rowBase + m) * K + k0 + kq * 4);
            As[kq*4+0][m] = a.x; As[kq*4+1][m] = a.y;
            As[kq*4+2][m] = a.z; As[kq*4+3][m] = a.w;
            float4 b = *(const float4*)(W + (size_t)(jbase + m) * K + k0 + kq * 4);
            Bs[kq*4+0][m] = b.x; Bs[kq*4+1][m] = b.y;
            Bs[kq*4+2][m] = b.z; Bs[kq*4+3][m] = b.w;
        }
        __syncthreads();
#pragma unroll
        for (int k = 0; k < 16; ++k) {
            float a[8], b[8];
            *(float4*)&a[0] = *(const float4*)&As[k][ty * 8];
            *(float4*)&a[4] = *(const float4*)&As[k][ty * 8 + 4];
            *(float4*)&b[0] = *(const float4*)&Bs[k][tx * 8];
            *(float4*)&b[4] = *(const float4*)&Bs[k][tx * 8 + 4];
#pragma unroll
            for (int i = 0; i < 8; ++i)
#pragma unroll
                for (int j = 0; j < 8; ++j) acc[i][j] += a[i] * b[j];
        }
        __syncthreads();
    }

#pragma unroll
    for (int i = 0; i < 8; ++i) {
        size_t base = (size_t)(rowBase + ty * 8 + i) * 4096 + bn * 128 + tx * 8;
        *(float4*)(XP + base)     = make_float4(acc[i][0], acc[i][1], acc[i][2], acc[i][3]);
        *(float4*)(XP + base + 4) = make_float4(acc[i][4], acc[i][5], acc[i][6], acc[i][7]);
    }
}

// ---------------------------------------------------------------------------
// One LSTM step: for each (b, j): 4 gate dot products over h_prev (K=1024),
// add xproj (or compute the x-dot if no workspace), combine gates, update c,
// write h_next. grid = (64 j-tiles, 4 b-tiles), block = 256 (16 j x 16 b).
// ---------------------------------------------------------------------------
template<int USE_XP>
__global__ __launch_bounds__(256) void lstm_step(
    const float* __restrict__ xp_t,    // [B][4][H] (if USE_XP)
    const float* __restrict__ x_t,     // [B][D]    (if !USE_XP)
    const float* __restrict__ h_prev,  // [B][H]
    float* __restrict__ h_next,        // [B][H]
    float* __restrict__ c,             // [B][H] in-out
    const float* __restrict__ Whi, const float* __restrict__ Whf,
    const float* __restrict__ Who, const float* __restrict__ Whc,
    const float* __restrict__ Wxi, const float* __restrict__ Wxf,
    const float* __restrict__ Wxo, const float* __restrict__ Wxc)
{
    __shared__ float hs[16 * 1024];    // 16 h-rows, 64 KB

    int tid = threadIdx.x;
    int bBase = blockIdx.y * 16;

#pragma unroll
    for (int i = 0; i < 16; ++i) {
        int f4 = tid + i * 256;        // 0..4095 float4 slots
        int row = f4 >> 8, c4 = f4 & 255;
        *(float4*)&hs[row * 1024 + c4 * 4] =
            *(const float4*)(h_prev + (size_t)(bBase + row) * 1024 + c4 * 4);
    }
    __syncthreads();

    int tx = tid & 15, ty = tid >> 4;
    int j = blockIdx.x * 16 + tx;
    int b = bBase + ty;

    float ai = 0.f, af = 0.f, ao = 0.f, ac = 0.f;
    const float* hrow = hs + ty * 1024;
    const float* wi = Whi + (size_t)j * 1024;
    const float* wf = Whf + (size_t)j * 1024;
    const float* wo = Who + (size_t)j * 1024;
    const float* wc = Whc + (size_t)j * 1024;

    for (int k = 0; k < 1024; k += 4) {
        float4 hv = *(const float4*)&hrow[k];
        float4 vi = *(const float4*)&wi[k];
        float4 vf = *(const float4*)&wf[k];
        float4 vo = *(const float4*)&wo[k];
        float4 vc = *(const float4*)&wc[k];
        ai += hv.x*vi.x + hv.y*vi.y + hv.z*vi.z + hv.w*vi.w;
        af += hv.x*vf.x + hv.y*vf.y + hv.z*vf.z + hv.w*vf.w;
        ao += hv.x*vo.x + hv.y*vo.y + hv.z*vo.z + hv.w*vo.w;
        ac += hv.x*vc.x + hv.y*vc.y + hv.z*vc.z + hv.w*vc.w;
    }

    if (USE_XP) {
        ai += xp_t[((size_t)b * 4 + 0) * 1024 + j];
        af += xp_t[((size_t)b * 4 + 1) * 1024 + j];
        ao += xp_t[((size_t)b * 4 + 2) * 1024 + j];
        ac += xp_t[((size_t)b * 4 + 3) * 1024 + j];
    } else {
        const float* xrow = x_t + (size_t)b * DIM;
        const float* ui = Wxi + (size_t)j * 1024;
        const float* uf = Wxf + (size_t)j * 1024;
        const float* uo = Wxo + (size_t)j * 1024;
        const float* uc = Wxc + (size_t)j * 1024;
        for (int k = 0; k < 1024; k += 4) {
            float4 xv = *(const float4*)&xrow[k];
            float4 vi = *(const float4*)&ui[k];
            float4 vf = *(const float4*)&uf[k];
            float4 vo = *(const float4*)&uo[k];
            float4 vc = *(const float4*)&uc[k];
            ai += xv.x*vi.x + xv.y*vi.y + xv.z*vi.z + xv.w*vi.w;
            af += xv.x*vf.x + xv.y*vf.y + xv.z*vf.z + xv.w*vf.w;
            ao += xv.x*vo.x + xv.y*vo.y + xv.z*vo.z + xv.w*vo.w;
            ac += xv.x*vc.x + xv.y*vc.y + xv.z*vc.z + xv.w*vc.w;
        }
    }

    float gi = 1.f / (1.f + expf(-ai));
    float gf = 1.f / (1.f + expf(-af));
    float go = 1.f / (1.f + expf(-ao));
    float gc = tanhf(ac);

    size_t idx = (size_t)b * 1024 + j;
    float cn = gf * c[idx] + gi * gc;
    c[idx] = cn;
    h_next[idx] = go * tanhf(cn);
}

// ---------------------------------------------------------------------------
// out_t[b][j] = sum_k h[b][k] * Wout[j][k]
// ---------------------------------------------------------------------------
__global__ __launch_bounds__(256) void out_gemm(
    const float* __restrict__ h, const float* __restrict__ Wout,
    float* __restrict__ out_t)
{
    __shared__ float hs[16 * 1024];
    int tid = threadIdx.x;
    int bBase = blockIdx.y * 16;

#pragma unroll
    for (int i = 0; i < 16; ++i) {
        int f4 = tid + i * 256;
        int row = f4 >> 8, c4 = f4 & 255;
        *(float4*)&hs[row * 1024 + c4 * 4] =
            *(const float4*)(h + (size_t)(bBase + row) * 1024 + c4 * 4);
    }
    __syncthreads();

    int tx = tid & 15, ty = tid >> 4;
    int j = blockIdx.x * 16 + tx;
    int b = bBase + ty;

    float a0 = 0.f, a1 = 0.f, a2 = 0.f, a3 = 0.f;
    const float* hrow = hs + ty * 1024;
    const float* wrow = Wout + (size_t)j * 1024;
    for (int k = 0; k < 1024; k += 4) {
        float4 hv = *(const float4*)&hrow[k];
        float4 wv = *(const float4*)&wrow[k];
        a0 += hv.x * wv.x; a1 += hv.y * wv.y;
        a2 += hv.z * wv.z; a3 += hv.w * wv.w;
    }
    out_t[(size_t)b * 1024 + j] = (a0 + a1) + (a2 + a3);
}

// ---------------------------------------------------------------------------
extern "C" void kernel_launch(void* const* d_in, const int* in_sizes, int n_in,
                              void* d_out, int out_size, void* d_ws, size_t ws_size,
                              hipStream_t stream)
{
    const float* x   = (const float*)d_in[0];
    const float* h0  = (const float*)d_in[1];
    const float* c0  = (const float*)d_in[2];
    const float* Wxi = (const float*)d_in[3];
    const float* Wxf = (const float*)d_in[4];
    const float* Wxo = (const float*)d_in[5];
    const float* Wxc = (const float*)d_in[6];
    const float* Whi = (const float*)d_in[7];
    const float* Whf = (const float*)d_in[8];
    const float* Who = (const float*)d_in[9];
    const float* Whc = (const float*)d_in[10];
    const float* Wout = (const float*)d_in[11];
    float* out = (float*)d_out;

    const size_t BH = (size_t)BATCH * HID;
    const size_t xp_bytes    = (size_t)T_STEPS * BATCH * 4 * HID * sizeof(float);
    const size_t state_bytes = 3 * BH * sizeof(float);
    bool use_xp = ws_size >= xp_bytes + state_bytes;

    char* ws = (char*)d_ws;
    float* xp = nullptr;
    float* hbuf;
    if (use_xp) { xp = (float*)ws; hbuf = (float*)(ws + xp_bytes); }
    else        { hbuf = (float*)ws; }
    float* cbuf = hbuf + 2 * BH;

    hipMemcpyAsync(hbuf, h0, BH * sizeof(float), hipMemcpyDeviceToDevice, stream);
    hipMemcpyAsync(cbuf, c0, BH * sizeof(float), hipMemcpyDeviceToDevice, stream);

    if (use_xp) {
        xproj_gemm<<<dim3(128, 32), 256, 0, stream>>>(x, Wxi, Wxf, Wxo, Wxc, xp);
    }

    for (int t = 0; t < T_STEPS; ++t) {
        const float* hp = hbuf + (size_t)(t & 1) * BH;
        float*       hn = hbuf + (size_t)((t + 1) & 1) * BH;
        if (use_xp) {
            lstm_step<1><<<dim3(64, 4), 256, 0, stream>>>(
                xp + (size_t)t * BATCH * 4 * HID, nullptr, hp, hn, cbuf,
                Whi, Whf, Who, Whc, nullptr, nullptr, nullptr, nullptr);
        } else {
            lstm_step<0><<<dim3(64, 4), 256, 0, stream>>>(
                nullptr, x + (size_t)t * BATCH * DIM, hp, hn, cbuf,
                Whi, Whf, Who, Whc, Wxi, Wxf, Wxo, Wxc);
        }
        out_gemm<<<dim3(64, 4), 256, 0, stream>>>(hn, Wout, out + (size_t)t * BH);
    }
}

// Round 2
// 47881.747 us; speedup vs baseline: 1.4097x; 1.4097x over previous
//
#include <hip/hip_runtime.h>
#include <hip/hip_bf16.h>
#include <hip/hip_cooperative_groups.h>
#include <math.h>

namespace cg = cooperative_groups;

#define T_STEPS 256
#define BATCH   64
#define DIM     1024
#define HID     1024

// ---------------------------------------------------------------------------
// xproj GEMM (fp32, 128x128 tile): XP[row][g*1024+j] = sum_k X[row][k]*Wg[j][k]
// ---------------------------------------------------------------------------
__global__ __launch_bounds__(256) void xproj_gemm(
    const float* __restrict__ X,
    const float* __restrict__ W0, const float* __restrict__ W1,
    const float* __restrict__ W2, const float* __restrict__ W3,
    float* __restrict__ XP)
{
    const int K = 1024;
    __shared__ float As[16][128];
    __shared__ float Bs[16][128];

    int bm = blockIdx.x;
    int bn = blockIdx.y;
    const float* W = (bn < 8) ? W0 : (bn < 16) ? W1 : (bn < 24) ? W2 : W3;
    int jbase   = (bn * 128) & 1023;
    int rowBase = bm * 128;

    int tid = threadIdx.x;
    int tx = tid & 15, ty = tid >> 4;

    float acc[8][8];
#pragma unroll
    for (int i = 0; i < 8; ++i)
#pragma unroll
        for (int j = 0; j < 8; ++j) acc[i][j] = 0.f;

    for (int k0 = 0; k0 < K; k0 += 16) {
#pragma unroll
        for (int i = 0; i < 2; ++i) {
            int fl = tid * 2 + i;
            int m  = fl >> 2;
            int kq = fl & 3;
            float4 a = *(const float4*)(X + (size_t)(rowBase + m) * K + k0 + kq * 4);
            As[kq*4+0][m] = a.x; As[kq*4+1][m] = a.y;
            As[kq*4+2][m] = a.z; As[kq*4+3][m] = a.w;
            float4 b = *(const float4*)(W + (size_t)(jbase + m) * K + k0 + kq * 4);
            Bs[kq*4+0][m] = b.x; Bs[kq*4+1][m] = b.y;
            Bs[kq*4+2][m] = b.z; Bs[kq*4+3][m] = b.w;
        }
        __syncthreads();
#pragma unroll
        for (int k = 0; k < 16; ++k) {
            float a[8], b[8];
            *(float4*)&a[0] = *(const float4*)&As[k][ty * 8];
            *(float4*)&a[4] = *(const float4*)&As[k][ty * 8 + 4];
            *(float4*)&b[0] = *(const float4*)&Bs[k][tx * 8];
            *(float4*)&b[4] = *(const float4*)&Bs[k][tx * 8 + 4];
#pragma unroll
            for (int i = 0; i < 8; ++i)
#pragma unroll
                for (int j = 0; j < 8; ++j) acc[i][j] += a[i] * b[j];
        }
        __syncthreads();
    }

#pragma unroll
    for (int i = 0; i < 8; ++i) {
        size_t base = (size_t)(rowBase + ty * 8 + i) * 4096 + bn * 128 + tx * 8;
        *(float4*)(XP + base)     = make_float4(acc[i][0], acc[i][1], acc[i][2], acc[i][3]);
        *(float4*)(XP + base + 4) = make_float4(acc[i][4], acc[i][5], acc[i][6], acc[i][7]);
    }
}

// ---------------------------------------------------------------------------
// pack4: PW[k][n'] = Wg[j][k], n' = (j>>2)*16 + g*4 + (j&3). 32x32 LDS tiles.
// grid = (32 jt, 32 kt, 4 g)
// ---------------------------------------------------------------------------
__global__ __launch_bounds__(256) void pack4(
    const float* __restrict__ W0, const float* __restrict__ W1,
    const float* __restrict__ W2, const float* __restrict__ W3,
    float* __restrict__ dst)
{
    __shared__ float tile[32][33];
    int jt = blockIdx.x, kt = blockIdx.y, g = blockIdx.z;
    const float* W = (g == 0) ? W0 : (g == 1) ? W1 : (g == 2) ? W2 : W3;
    int tid = threadIdx.x;
#pragma unroll
    for (int i = 0; i < 4; ++i) {
        int e = i * 256 + tid;
        int r = e >> 5, c = e & 31;              // r = j-row, c = k-col
        tile[r][c] = W[(size_t)(jt * 32 + r) * 1024 + kt * 32 + c];
    }
    __syncthreads();
#pragma unroll
    for (int i = 0; i < 4; ++i) {
        int e = i * 256 + tid;
        int rk = e >> 5, cj = e & 31;            // rk = k-row, cj = j-col
        int j = jt * 32 + cj;
        int np = ((j >> 2) << 4) + g * 4 + (j & 3);
        dst[(size_t)(kt * 32 + rk) * 4096 + np] = tile[cj][rk];
    }
}

// pack_wo: PO[k][j] = Wout[j][k]
__global__ __launch_bounds__(256) void pack_wo(
    const float* __restrict__ W, float* __restrict__ dst)
{
    __shared__ float tile[32][33];
    int jt = blockIdx.x, kt = blockIdx.y;
    int tid = threadIdx.x;
#pragma unroll
    for (int i = 0; i < 4; ++i) {
        int e = i * 256 + tid;
        int r = e >> 5, c = e & 31;
        tile[r][c] = W[(size_t)(jt * 32 + r) * 1024 + kt * 32 + c];
    }
    __syncthreads();
#pragma unroll
    for (int i = 0; i < 4; ++i) {
        int e = i * 256 + tid;
        int rk = e >> 5, cj = e & 31;
        dst[(size_t)(kt * 32 + rk) * 1024 + jt * 32 + cj] = tile[cj][rk];
    }
}

// transpose h0[b][k] -> hT[k][b]
__global__ __launch_bounds__(256) void transpose_h0(
    const float* __restrict__ h0, float* __restrict__ hT)
{
    int e = blockIdx.x * 256 + threadIdx.x;   // 65536 elems
    int k = e >> 6, b = e & 63;
    hT[k * 64 + b] = h0[(size_t)b * 1024 + k];
}

// xT[t][k][b] = x[t][b][k]; grid (16 kt, 256 t)
__global__ __launch_bounds__(256) void xT_build(
    const float* __restrict__ x, float* __restrict__ xT)
{
    __shared__ float tile[64][65];
    int kt = blockIdx.x, t = blockIdx.y;
    int tid = threadIdx.x;
#pragma unroll
    for (int i = 0; i < 16; ++i) {
        int e = i * 256 + tid;
        int r = e >> 6, c = e & 63;               // r = b, c = k-off
        tile[r][c] = x[((size_t)t * 64 + r) * 1024 + kt * 64 + c];
    }
    __syncthreads();
#pragma unroll
    for (int i = 0; i < 16; ++i) {
        int e = i * 256 + tid;
        int r = e >> 6, c = e & 63;               // r = k-off, c = b
        xT[(size_t)t * 65536 + (kt * 64 + r) * 64 + c] = tile[c][r];
    }
}

// ---------------------------------------------------------------------------
// Persistent cooperative LSTM loop.
// grid = 256 blocks x 512 threads. Block ng owns j in {4ng..4ng+3} (all gates).
// Wave kq (tid>>6) covers k in [128kq, 128kq+128); lane = b.
// XMODE: 0 = xp precomputed; 1 = xT path (fold x-GEMM in); 2 = direct x.
// ---------------------------------------------------------------------------
template<int XMODE>
__global__ __launch_bounds__(512, 1) void lstm_loop(
    const float* __restrict__ xp,
    const float* __restrict__ xsrc,
    const float* __restrict__ PW,
    const float* __restrict__ PX,
    const float* __restrict__ PO,
    const float* __restrict__ c0,
    float* __restrict__ hb0,
    float* __restrict__ hb1,
    float* __restrict__ out)
{
    __shared__ float red[8 * 64 * 17];
    const int tid  = threadIdx.x;
    const int lane = tid & 63;           // b
    const int kq   = tid >> 6;           // 0..7
    const int ng   = blockIdx.x;         // 0..255
    cg::grid_group grid = cg::this_grid();

    const float4* PW4 = (const float4*)PW;
    const float4* PX4 = (const float4*)PX;
    const float4* PO4 = (const float4*)PO;

    // combine-thread identity: tid<256 -> jj = tid&3, b = tid>>2
    float c_reg = 0.f;
    if (tid < 256) {
        int b = tid >> 2, jj = tid & 3;
        c_reg = c0[(size_t)b * 1024 + 4 * ng + jj];
    }

    for (int t = 0; t < T_STEPS; ++t) {
        const float* hcur = (t & 1) ? hb1 : hb0;
        float*       hnxt = (t & 1) ? hb0 : hb1;

        // ---------------- Phase A: gate preactivations ----------------
        float acc[16];
#pragma unroll
        for (int i = 0; i < 16; ++i) acc[i] = 0.f;

        {
            const int k0 = kq * 128;
#pragma unroll 4
            for (int k = k0; k < k0 + 128; ++k) {
                float hv = hcur[k * 64 + lane];
                float4 w0 = PW4[(size_t)k * 1024 + ng * 4 + 0];
                float4 w1 = PW4[(size_t)k * 1024 + ng * 4 + 1];
                float4 w2 = PW4[(size_t)k * 1024 + ng * 4 + 2];
                float4 w3 = PW4[(size_t)k * 1024 + ng * 4 + 3];
                acc[0]  += w0.x * hv; acc[1]  += w0.y * hv;
                acc[2]  += w0.z * hv; acc[3]  += w0.w * hv;
                acc[4]  += w1.x * hv; acc[5]  += w1.y * hv;
                acc[6]  += w1.z * hv; acc[7]  += w1.w * hv;
                acc[8]  += w2.x * hv; acc[9]  += w2.y * hv;
                acc[10] += w2.z * hv; acc[11] += w2.w * hv;
                acc[12] += w3.x * hv; acc[13] += w3.y * hv;
                acc[14] += w3.z * hv; acc[15] += w3.w * hv;

                if (XMODE != 0) {
                    float xv;
                    if (XMODE == 1) xv = xsrc[(size_t)t * 65536 + k * 64 + lane];
                    else            xv = xsrc[((size_t)t * 64 + lane) * 1024 + k];
                    float4 u0 = PX4[(size_t)k * 1024 + ng * 4 + 0];
                    float4 u1 = PX4[(size_t)k * 1024 + ng * 4 + 1];
                    float4 u2 = PX4[(size_t)k * 1024 + ng * 4 + 2];
                    float4 u3 = PX4[(size_t)k * 1024 + ng * 4 + 3];
                    acc[0]  += u0.x * xv; acc[1]  += u0.y * xv;
                    acc[2]  += u0.z * xv; acc[3]  += u0.w * xv;
                    acc[4]  += u1.x * xv; acc[5]  += u1.y * xv;
                    acc[6]  += u1.z * xv; acc[7]  += u1.w * xv;
                    acc[8]  += u2.x * xv; acc[9]  += u2.y * xv;
                    acc[10] += u2.z * xv; acc[11] += u2.w * xv;
                    acc[12] += u3.x * xv; acc[13] += u3.y * xv;
                    acc[14] += u3.z * xv; acc[15] += u3.w * xv;
                }
            }
        }
#pragma unroll
        for (int i = 0; i < 16; ++i)
            red[(kq * 64 + lane) * 17 + i] = acc[i];
        __syncthreads();

        // ---------------- combine: gates -> c,h ----------------
        if (tid < 256) {
            int b = tid >> 2, jj = tid & 3;
            float pre[4];
#pragma unroll
            for (int g = 0; g < 4; ++g) {
                float s = 0.f;
#pragma unroll
                for (int q = 0; q < 8; ++q)
                    s += red[(q * 64 + b) * 17 + g * 4 + jj];
                pre[g] = s;
            }
            if (XMODE == 0) {
                size_t xb = ((size_t)t * 64 + b) * 4096 + 4 * ng + jj;
                pre[0] += xp[xb + 0 * 1024];
                pre[1] += xp[xb + 1 * 1024];
                pre[2] += xp[xb + 2 * 1024];
                pre[3] += xp[xb + 3 * 1024];
            }
            float gi = 1.f / (1.f + expf(-pre[0]));
            float gf = 1.f / (1.f + expf(-pre[1]));
            float go = 1.f / (1.f + expf(-pre[2]));
            float cn = gf * c_reg + gi * tanhf(pre[3]);
            c_reg = cn;
            float hn = go * tanhf(cn);
            hnxt[(4 * ng + jj) * 64 + b] = hn;
        }
        __threadfence();
        grid.sync();

        // ---------------- Phase B: out = h(t+1) @ Wout^T ----------------
        float ao[4] = {0.f, 0.f, 0.f, 0.f};
        {
            const int k0 = kq * 128;
#pragma unroll 4
            for (int k = k0; k < k0 + 128; ++k) {
                float hv = hnxt[k * 64 + lane];
                float4 w = PO4[(size_t)k * 256 + ng];
                ao[0] += w.x * hv; ao[1] += w.y * hv;
                ao[2] += w.z * hv; ao[3] += w.w * hv;
            }
        }
#pragma unroll
        for (int i = 0; i < 4; ++i)
            red[(kq * 64 + lane) * 17 + i] = ao[i];
        __syncthreads();
        if (tid < 256) {
            int b = tid >> 2, jj = tid & 3;
            float s = 0.f;
#pragma unroll
            for (int q = 0; q < 8; ++q)
                s += red[(q * 64 + b) * 17 + jj];
            out[(size_t)t * 65536 + b * 1024 + 4 * ng + jj] = s;
        }
        __syncthreads();   // protect red before next step's Phase A writes
    }
}

// ---------------------------------------------------------------------------
extern "C" void kernel_launch(void* const* d_in, const int* in_sizes, int n_in,
                              void* d_out, int out_size, void* d_ws, size_t ws_size,
                              hipStream_t stream)
{
    const float* x   = (const float*)d_in[0];
    const float* h0  = (const float*)d_in[1];
    const float* c0  = (const float*)d_in[2];
    const float* Wxi = (const float*)d_in[3];
    const float* Wxf = (const float*)d_in[4];
    const float* Wxo = (const float*)d_in[5];
    const float* Wxc = (const float*)d_in[6];
    const float* Whi = (const float*)d_in[7];
    const float* Whf = (const float*)d_in[8];
    const float* Who = (const float*)d_in[9];
    const float* Whc = (const float*)d_in[10];
    const float* Wout = (const float*)d_in[11];
    float* out = (float*)d_out;

    float* ws = (float*)d_ws;
    const size_t PW_N = (size_t)1024 * 4096;
    const size_t PO_N = (size_t)1024 * 1024;
    const size_t HB_N = (size_t)1024 * 64;
    const size_t XP_N = (size_t)T_STEPS * 64 * 4096;
    const size_t XT_N = (size_t)T_STEPS * 64 * 1024;

    float* PW  = ws;               ws += PW_N;
    float* PO  = ws;               ws += PO_N;
    float* hb0 = ws;               ws += HB_N;
    float* hb1 = ws;               ws += HB_N;
    const size_t base_floats = PW_N + PO_N + 2 * HB_N;
    const size_t avail = ws_size / sizeof(float);

    int xmode;
    float* xp = nullptr;
    float* PX = nullptr;
    float* xT = nullptr;
    if (avail >= base_floats + XP_N)              { xmode = 0; xp = ws; }
    else if (avail >= base_floats + PW_N + XT_N)  { xmode = 1; PX = ws; xT = ws + PW_N; }
    else                                          { xmode = 2; PX = ws; }

    // weight packing + h0 transpose
    pack4<<<dim3(32, 32, 4), 256, 0, stream>>>(Whi, Whf, Who, Whc, PW);
    pack_wo<<<dim3(32, 32), 256, 0, stream>>>(Wout, PO);
    transpose_h0<<<256, 256, 0, stream>>>(h0, hb0);

    if (xmode == 0) {
        xproj_gemm<<<dim3(128, 32), 256, 0, stream>>>(x, Wxi, Wxf, Wxo, Wxc, xp);
    } else {
        pack4<<<dim3(32, 32, 4), 256, 0, stream>>>(Wxi, Wxf, Wxo, Wxc, PX);
        if (xmode == 1) xT_build<<<dim3(16, 256), 256, 0, stream>>>(x, xT);
    }

    const float* xsrc = (xmode == 1) ? (const float*)xT : x;
    void* args[9];
    args[0] = (void*)&xp;
    args[1] = (void*)&xsrc;
    args[2] = (void*)&PW;
    args[3] = (void*)&PX;
    args[4] = (void*)&PO;
    args[5] = (void*)&c0;
    args[6] = (void*)&hb0;
    args[7] = (void*)&hb1;
    args[8] = (void*)&out;

    const void* fn = (xmode == 0) ? (const void*)lstm_loop<0>
                   : (xmode == 1) ? (const void*)lstm_loop<1>
                                  : (const void*)lstm_loop<2>;
    hipLaunchCooperativeKernel(fn, dim3(256), dim3(512), args, 0, stream);
}

// Round 3
// 14828.920 us; speedup vs baseline: 4.5519x; 3.2289x over previous
//
#include <hip/hip_runtime.h>
#include <hip/hip_bf16.h>
#include <hip/hip_cooperative_groups.h>
#include <math.h>
#include <string.h>

namespace cg = cooperative_groups;

#define T_STEPS 256
#define BATCH   64
#define DIM     1024
#define HID     1024

typedef __attribute__((ext_vector_type(8))) short short8_t;  // 8 bf16
typedef __attribute__((ext_vector_type(4))) float f32x4;

// ---------------------------------------------------------------------------
// pack4: PWb[ng][k][16] : PWb[(j>>2)*16384 + k*16 + g*4 + (j&3)] = Wg[j][k]
// grid (32 jt, 32 kt, 4 g), 32x32 LDS transpose tiles.
// ---------------------------------------------------------------------------
__global__ __launch_bounds__(256) void pack4(
    const float* __restrict__ W0, const float* __restrict__ W1,
    const float* __restrict__ W2, const float* __restrict__ W3,
    float* __restrict__ dst)
{
    __shared__ float tile[32][33];
    int jt = blockIdx.x, kt = blockIdx.y, g = blockIdx.z;
    const float* W = (g == 0) ? W0 : (g == 1) ? W1 : (g == 2) ? W2 : W3;
    int tid = threadIdx.x;
#pragma unroll
    for (int i = 0; i < 4; ++i) {
        int e = i * 256 + tid;
        int r = e >> 5, c = e & 31;              // r = j-row, c = k-col
        tile[r][c] = W[(size_t)(jt * 32 + r) * 1024 + kt * 32 + c];
    }
    __syncthreads();
#pragma unroll
    for (int i = 0; i < 4; ++i) {
        int e = i * 256 + tid;
        int rk = e >> 5, cj = e & 31;            // rk = k-row, cj = j-col
        int j = jt * 32 + cj;
        int k = kt * 32 + rk;
        dst[(size_t)(j >> 2) * 16384 + k * 16 + g * 4 + (j & 3)] = tile[cj][rk];
    }
}

// pack_wo: POb[ng][k][4] : dst[(j>>2)*4096 + k*4 + (j&3)] = Wout[j][k]
__global__ __launch_bounds__(256) void pack_wo(
    const float* __restrict__ W, float* __restrict__ dst)
{
    __shared__ float tile[32][33];
    int jt = blockIdx.x, kt = blockIdx.y;
    int tid = threadIdx.x;
#pragma unroll
    for (int i = 0; i < 4; ++i) {
        int e = i * 256 + tid;
        int r = e >> 5, c = e & 31;
        tile[r][c] = W[(size_t)(jt * 32 + r) * 1024 + kt * 32 + c];
    }
    __syncthreads();
#pragma unroll
    for (int i = 0; i < 4; ++i) {
        int e = i * 256 + tid;
        int rk = e >> 5, cj = e & 31;
        int j = jt * 32 + cj;
        int k = kt * 32 + rk;
        dst[(size_t)(j >> 2) * 4096 + k * 4 + (j & 3)] = tile[cj][rk];
    }
}

// transpose h0[b][k] -> hT[k][b]
__global__ __launch_bounds__(256) void transpose_h0(
    const float* __restrict__ h0, float* __restrict__ hT)
{
    int e = blockIdx.x * 256 + threadIdx.x;   // 65536
    int k = e >> 6, b = e & 63;
    hT[k * 64 + b] = h0[(size_t)b * 1024 + k];
}

// ---------------------------------------------------------------------------
// xproj bf16 MFMA GEMM: xpb[m][n] = sum_k X[m][k] * Wg[n&1023][k], bf16 out.
// M=16384, N=4096, K=1024. 128x128 tile, 256 thr (4 waves 2x2), K-step 32.
// fp32 inputs converted to bf16 during reg-staging.
// ---------------------------------------------------------------------------
__global__ __launch_bounds__(256) void xproj_mfma(
    const float* __restrict__ X,
    const float* __restrict__ W0, const float* __restrict__ W1,
    const float* __restrict__ W2, const float* __restrict__ W3,
    __hip_bfloat16* __restrict__ xpb)
{
    __shared__ short8_t As[4 * 128];   // [kg][m] 8 bf16 each  (8 KB)
    __shared__ short8_t Bs[4 * 128];   // [kg][n]              (8 KB)

    const int bm = blockIdx.x;               // 0..127
    const int bn = blockIdx.y;               // 0..31
    const float* W = (bn < 8) ? W0 : (bn < 16) ? W1 : (bn < 24) ? W2 : W3;
    const int jbase = (bn & 7) * 128;
    const int m0 = bm * 128;

    const int tid  = threadIdx.x;
    const int lane = tid & 63;
    const int wave = tid >> 6;               // 0..3
    const int wm = wave >> 1, wn = wave & 1;
    const int q  = lane >> 4;                // k-group of this lane
    const int lr = lane & 15;

    f32x4 acc[4][4];
#pragma unroll
    for (int i = 0; i < 4; ++i)
#pragma unroll
        for (int j = 0; j < 4; ++j) acc[i][j] = (f32x4){0.f, 0.f, 0.f, 0.f};

    for (int k0 = 0; k0 < 1024; k0 += 32) {
        // stage: slots s = tid and tid+256; kg = s&3, row = s>>2
#pragma unroll
        for (int ss = 0; ss < 2; ++ss) {
            int s  = tid + ss * 256;
            int kg = s & 3, r = s >> 2;
            const float* xa = X + (size_t)(m0 + r) * 1024 + k0 + kg * 8;
            const float* wb = W + (size_t)(jbase + r) * 1024 + k0 + kg * 8;
            float4 a0 = *(const float4*)(xa);
            float4 a1 = *(const float4*)(xa + 4);
            float4 b0 = *(const float4*)(wb);
            float4 b1 = *(const float4*)(wb + 4);
            union { short8_t v; ushort u[8]; } ua, ub;
            float af[8] = {a0.x,a0.y,a0.z,a0.w,a1.x,a1.y,a1.z,a1.w};
            float bf[8] = {b0.x,b0.y,b0.z,b0.w,b1.x,b1.y,b1.z,b1.w};
#pragma unroll
            for (int e = 0; e < 8; ++e) {
                __hip_bfloat16 ha = __float2bfloat16(af[e]);
                __hip_bfloat16 hb = __float2bfloat16(bf[e]);
                ua.u[e] = *reinterpret_cast<ushort*>(&ha);
                ub.u[e] = *reinterpret_cast<ushort*>(&hb);
            }
            As[kg * 128 + r] = ua.v;
            Bs[kg * 128 + r] = ub.v;
        }
        __syncthreads();

        short8_t a[4], b[4];
#pragma unroll
        for (int mi = 0; mi < 4; ++mi)
            a[mi] = As[q * 128 + wm * 64 + mi * 16 + lr];
#pragma unroll
        for (int nj = 0; nj < 4; ++nj)
            b[nj] = Bs[q * 128 + wn * 64 + nj * 16 + lr];
#pragma unroll
        for (int mi = 0; mi < 4; ++mi)
#pragma unroll
            for (int nj = 0; nj < 4; ++nj)
                acc[mi][nj] = __builtin_amdgcn_mfma_f32_16x16x32_bf16(
                    a[mi], b[nj], acc[mi][nj], 0, 0, 0);
        __syncthreads();
    }

    // epilogue: rows m = m0 + wm*64 + mi*16 + q*4 + r ; col n = bn*128 + wn*64 + nj*16 + lr
#pragma unroll
    for (int mi = 0; mi < 4; ++mi) {
#pragma unroll
        for (int nj = 0; nj < 4; ++nj) {
#pragma unroll
            for (int r = 0; r < 4; ++r) {
                int m = m0 + wm * 64 + mi * 16 + q * 4 + r;
                int n = bn * 128 + wn * 64 + nj * 16 + lr;
                xpb[(size_t)m * 4096 + n] = __float2bfloat16(acc[mi][nj][r]);
            }
        }
    }
}

// ---------------------------------------------------------------------------
// Persistent cooperative LSTM loop, weights pinned in LDS.
// 256 blocks x 512 thr. Block ng owns j in {4ng..4ng+3} (x4 gates).
// Wave kq: k in [128kq,128kq+128); lane = b.
// XFOLD=0: xp precomputed (bf16). XFOLD=1: fold x-proj, PXb streamed global.
// ---------------------------------------------------------------------------
template<int XFOLD>
__global__ __launch_bounds__(512, 1) void lstm_loop2(
    const __hip_bfloat16* __restrict__ xp,   // [T][64][4096] bf16
    const float* __restrict__ x,             // [T][64][1024] (XFOLD=1)
    const float* __restrict__ PWb,           // [256][1024][16]
    const float* __restrict__ PXb,           // [256][1024][16] (XFOLD=1)
    const float* __restrict__ POb,           // [256][1024][4]
    const float* __restrict__ c0,
    float* __restrict__ hb0,
    float* __restrict__ hb1,
    float* __restrict__ out)
{
    __shared__ float WL[1024 * 16];          // 64 KB  Wh slice
    __shared__ float OL[1024 * 4];           // 16 KB  Wout slice
    __shared__ float red[8 * 64 * 17];       // 34.8 KB reduction

    const int tid  = threadIdx.x;
    const int lane = tid & 63;               // b
    const int kq   = tid >> 6;               // 0..7
    const int ng   = blockIdx.x;             // 0..255
    cg::grid_group grid = cg::this_grid();

    // one-time LDS weight load (fully coalesced, block-contiguous)
    {
        const float4* srcW = (const float4*)(PWb + (size_t)ng * 16384);
        float4* dstW = (float4*)WL;
        for (int i = tid; i < 4096; i += 512) dstW[i] = srcW[i];
        const float4* srcO = (const float4*)(POb + (size_t)ng * 4096);
        float4* dstO = (float4*)OL;
        for (int i = tid; i < 1024; i += 512) dstO[i] = srcO[i];
    }
    float c_reg = 0.f;
    if (tid < 256) c_reg = c0[(size_t)(tid >> 2) * 1024 + 4 * ng + (tid & 3)];
    __syncthreads();

    const f32x4* WL4 = (const f32x4*)WL;
    const f32x4* OL4 = (const f32x4*)OL;

    for (int t = 0; t < T_STEPS; ++t) {
        const float* hcur = (t & 1) ? hb1 : hb0;
        float*       hnxt = (t & 1) ? hb0 : hb1;

        // prefetch this step's xp values (hide post-invalidate HBM latency)
        float xpv[4] = {0.f, 0.f, 0.f, 0.f};
        if (XFOLD == 0 && tid < 256) {
            int b = tid >> 2, jj = tid & 3;
            size_t base = ((size_t)t * 64 + b) * 4096 + 4 * ng + jj;
            xpv[0] = __bfloat162float(xp[base + 0 * 1024]);
            xpv[1] = __bfloat162float(xp[base + 1 * 1024]);
            xpv[2] = __bfloat162float(xp[base + 2 * 1024]);
            xpv[3] = __bfloat162float(xp[base + 3 * 1024]);
        }

        // ---------------- Phase A: gate preactivations ----------------
        float acc[16];
#pragma unroll
        for (int i = 0; i < 16; ++i) acc[i] = 0.f;

        {
            const int k0 = kq * 128;
#pragma unroll 2
            for (int k = k0; k < k0 + 128; ++k) {
                float hv = hcur[k * 64 + lane];
                f32x4 w0 = WL4[k * 4 + 0];
                f32x4 w1 = WL4[k * 4 + 1];
                f32x4 w2 = WL4[k * 4 + 2];
                f32x4 w3 = WL4[k * 4 + 3];
                acc[0]  += w0[0] * hv; acc[1]  += w0[1] * hv;
                acc[2]  += w0[2] * hv; acc[3]  += w0[3] * hv;
                acc[4]  += w1[0] * hv; acc[5]  += w1[1] * hv;
                acc[6]  += w1[2] * hv; acc[7]  += w1[3] * hv;
                acc[8]  += w2[0] * hv; acc[9]  += w2[1] * hv;
                acc[10] += w2[2] * hv; acc[11] += w2[3] * hv;
                acc[12] += w3[0] * hv; acc[13] += w3[1] * hv;
                acc[14] += w3[2] * hv; acc[15] += w3[3] * hv;
                if (XFOLD == 1) {
                    float xv = x[((size_t)t * 64 + lane) * 1024 + k];
                    const f32x4* PX4 = (const f32x4*)(PXb + (size_t)ng * 16384);
                    f32x4 u0 = PX4[k * 4 + 0];
                    f32x4 u1 = PX4[k * 4 + 1];
                    f32x4 u2 = PX4[k * 4 + 2];
                    f32x4 u3 = PX4[k * 4 + 3];
                    acc[0]  += u0[0] * xv; acc[1]  += u0[1] * xv;
                    acc[2]  += u0[2] * xv; acc[3]  += u0[3] * xv;
                    acc[4]  += u1[0] * xv; acc[5]  += u1[1] * xv;
                    acc[6]  += u1[2] * xv; acc[7]  += u1[3] * xv;
                    acc[8]  += u2[0] * xv; acc[9]  += u2[1] * xv;
                    acc[10] += u2[2] * xv; acc[11] += u2[3] * xv;
                    acc[12] += u3[0] * xv; acc[13] += u3[1] * xv;
                    acc[14] += u3[2] * xv; acc[15] += u3[3] * xv;
                }
            }
        }
#pragma unroll
        for (int i = 0; i < 16; ++i)
            red[(kq * 64 + lane) * 17 + i] = acc[i];
        __syncthreads();

        // ---------------- combine: gates -> c,h ----------------
        if (tid < 256) {
            int b = tid >> 2, jj = tid & 3;
            float pre[4];
#pragma unroll
            for (int g = 0; g < 4; ++g) {
                float s = 0.f;
#pragma unroll
                for (int qq = 0; qq < 8; ++qq)
                    s += red[(qq * 64 + b) * 17 + g * 4 + jj];
                pre[g] = s + xpv[g];
            }
            float gi = 1.f / (1.f + expf(-pre[0]));
            float gf = 1.f / (1.f + expf(-pre[1]));
            float go = 1.f / (1.f + expf(-pre[2]));
            float cn = gf * c_reg + gi * tanhf(pre[3]);
            c_reg = cn;
            hnxt[(4 * ng + jj) * 64 + b] = go * tanhf(cn);
        }
        grid.sync();

        // ---------------- Phase B: out(t) = h(t+1) @ Wout^T ----------------
        float ao[4] = {0.f, 0.f, 0.f, 0.f};
        {
            const int k0 = kq * 128;
#pragma unroll 2
            for (int k = k0; k < k0 + 128; ++k) {
                float hv = hnxt[k * 64 + lane];
                f32x4 w = OL4[k];
                ao[0] += w[0] * hv; ao[1] += w[1] * hv;
                ao[2] += w[2] * hv; ao[3] += w[3] * hv;
            }
        }
#pragma unroll
        for (int i = 0; i < 4; ++i)
            red[(kq * 64 + lane) * 17 + i] = ao[i];
        __syncthreads();
        if (tid < 256) {
            int b = tid >> 2, jj = tid & 3;
            float s = 0.f;
#pragma unroll
            for (int qq = 0; qq < 8; ++qq)
                s += red[(qq * 64 + b) * 17 + jj];
            out[(size_t)t * 65536 + b * 1024 + 4 * ng + jj] = s;
        }
        __syncthreads();   // red reused next step
    }
}

// ---------------------------------------------------------------------------
extern "C" void kernel_launch(void* const* d_in, const int* in_sizes, int n_in,
                              void* d_out, int out_size, void* d_ws, size_t ws_size,
                              hipStream_t stream)
{
    const float* x   = (const float*)d_in[0];
    const float* h0  = (const float*)d_in[1];
    const float* c0  = (const float*)d_in[2];
    const float* Wxi = (const float*)d_in[3];
    const float* Wxf = (const float*)d_in[4];
    const float* Wxo = (const float*)d_in[5];
    const float* Wxc = (const float*)d_in[6];
    const float* Whi = (const float*)d_in[7];
    const float* Whf = (const float*)d_in[8];
    const float* Who = (const float*)d_in[9];
    const float* Whc = (const float*)d_in[10];
    const float* Wout = (const float*)d_in[11];
    float* out = (float*)d_out;

    const size_t PW_BYTES  = (size_t)256 * 1024 * 16 * 4;        // 16 MB
    const size_t PO_BYTES  = (size_t)256 * 1024 * 4 * 4;         //  4 MB
    const size_t HB_BYTES  = (size_t)1024 * 64 * 4;              // 256 KB
    const size_t XPB_BYTES = (size_t)T_STEPS * 64 * 4096 * 2;    // 128 MB bf16

    char* ws = (char*)d_ws;
    float* PWb = (float*)ws;                 ws += PW_BYTES;
    float* POb = (float*)ws;                 ws += PO_BYTES;
    float* hb0 = (float*)ws;                 ws += HB_BYTES;
    float* hb1 = (float*)ws;                 ws += HB_BYTES;

    const size_t base_need = PW_BYTES + PO_BYTES + 2 * HB_BYTES;
    bool use_xp = ws_size >= base_need + XPB_BYTES;

    __hip_bfloat16* xpb = nullptr;
    float* PXb = nullptr;
    if (use_xp) {
        xpb = (__hip_bfloat16*)ws;
    } else {
        PXb = (float*)ws;                    // 16 MB (fits: base+16MB = 36.5MB)
    }

    pack4<<<dim3(32, 32, 4), 256, 0, stream>>>(Whi, Whf, Who, Whc, PWb);
    pack_wo<<<dim3(32, 32), 256, 0, stream>>>(Wout, POb);
    transpose_h0<<<256, 256, 0, stream>>>(h0, hb0);

    if (use_xp) {
        xproj_mfma<<<dim3(128, 32), 256, 0, stream>>>(x, Wxi, Wxf, Wxo, Wxc, xpb);
    } else {
        pack4<<<dim3(32, 32, 4), 256, 0, stream>>>(Wxi, Wxf, Wxo, Wxc, PXb);
    }

    void* args[9];
    args[0] = (void*)&xpb;
    args[1] = (void*)&x;
    args[2] = (void*)&PWb;
    args[3] = (void*)&PXb;
    args[4] = (void*)&POb;
    args[5] = (void*)&c0;
    args[6] = (void*)&hb0;
    args[7] = (void*)&hb1;
    args[8] = (void*)&out;

    const void* fn = use_xp ? (const void*)lstm_loop2<0>
                            : (const void*)lstm_loop2<1>;
    hipLaunchCooperativeKernel(fn, dim3(256), dim3(512), args, 0, stream);
}

// Round 4
// 7740.948 us; speedup vs baseline: 8.7197x; 1.9156x over previous
//
#include <hip/hip_runtime.h>
#include <hip/hip_bf16.h>
#include <math.h>
#include <string.h>

#define T_STEPS 256
#define BATCH   64
#define DIM     1024
#define HID     1024

typedef __attribute__((ext_vector_type(8))) short short8_t;  // 8 bf16
typedef __attribute__((ext_vector_type(4))) float f32x4;

// ---------------------------------------------------------------------------
// pack4: PWb[(j>>2)*16384 + k*16 + g*4 + (j&3)] = Wg[j][k]
// ---------------------------------------------------------------------------
__global__ __launch_bounds__(256) void pack4(
    const float* __restrict__ W0, const float* __restrict__ W1,
    const float* __restrict__ W2, const float* __restrict__ W3,
    float* __restrict__ dst)
{
    __shared__ float tile[32][33];
    int jt = blockIdx.x, kt = blockIdx.y, g = blockIdx.z;
    const float* W = (g == 0) ? W0 : (g == 1) ? W1 : (g == 2) ? W2 : W3;
    int tid = threadIdx.x;
#pragma unroll
    for (int i = 0; i < 4; ++i) {
        int e = i * 256 + tid;
        int r = e >> 5, c = e & 31;
        tile[r][c] = W[(size_t)(jt * 32 + r) * 1024 + kt * 32 + c];
    }
    __syncthreads();
#pragma unroll
    for (int i = 0; i < 4; ++i) {
        int e = i * 256 + tid;
        int rk = e >> 5, cj = e & 31;
        int j = jt * 32 + cj;
        int k = kt * 32 + rk;
        dst[(size_t)(j >> 2) * 16384 + k * 16 + g * 4 + (j & 3)] = tile[cj][rk];
    }
}

// pack_wo: POb[(j>>2)*4096 + k*4 + (j&3)] = Wout[j][k]
__global__ __launch_bounds__(256) void pack_wo(
    const float* __restrict__ W, float* __restrict__ dst)
{
    __shared__ float tile[32][33];
    int jt = blockIdx.x, kt = blockIdx.y;
    int tid = threadIdx.x;
#pragma unroll
    for (int i = 0; i < 4; ++i) {
        int e = i * 256 + tid;
        int r = e >> 5, c = e & 31;
        tile[r][c] = W[(size_t)(jt * 32 + r) * 1024 + kt * 32 + c];
    }
    __syncthreads();
#pragma unroll
    for (int i = 0; i < 4; ++i) {
        int e = i * 256 + tid;
        int rk = e >> 5, cj = e & 31;
        int j = jt * 32 + cj;
        int k = kt * 32 + rk;
        dst[(size_t)(j >> 2) * 4096 + k * 4 + (j & 3)] = tile[cj][rk];
    }
}

// transpose h0[b][k] -> hT[k][b]
__global__ __launch_bounds__(256) void transpose_h0(
    const float* __restrict__ h0, float* __restrict__ hT)
{
    int e = blockIdx.x * 256 + threadIdx.x;
    int k = e >> 6, b = e & 63;
    hT[k * 64 + b] = h0[(size_t)b * 1024 + k];
}

// ---------------------------------------------------------------------------
// xproj bf16 MFMA GEMM (unchanged from round 3; off critical path)
// ---------------------------------------------------------------------------
__global__ __launch_bounds__(256) void xproj_mfma(
    const float* __restrict__ X,
    const float* __restrict__ W0, const float* __restrict__ W1,
    const float* __restrict__ W2, const float* __restrict__ W3,
    __hip_bfloat16* __restrict__ xpb)
{
    __shared__ short8_t As[4 * 128];
    __shared__ short8_t Bs[4 * 128];

    const int bm = blockIdx.x;
    const int bn = blockIdx.y;
    const float* W = (bn < 8) ? W0 : (bn < 16) ? W1 : (bn < 24) ? W2 : W3;
    const int jbase = (bn & 7) * 128;
    const int m0 = bm * 128;

    const int tid  = threadIdx.x;
    const int lane = tid & 63;
    const int wave = tid >> 6;
    const int wm = wave >> 1, wn = wave & 1;
    const int q  = lane >> 4;
    const int lr = lane & 15;

    f32x4 acc[4][4];
#pragma unroll
    for (int i = 0; i < 4; ++i)
#pragma unroll
        for (int j = 0; j < 4; ++j) acc[i][j] = (f32x4){0.f, 0.f, 0.f, 0.f};

    for (int k0 = 0; k0 < 1024; k0 += 32) {
#pragma unroll
        for (int ss = 0; ss < 2; ++ss) {
            int s  = tid + ss * 256;
            int kg = s & 3, r = s >> 2;
            const float* xa = X + (size_t)(m0 + r) * 1024 + k0 + kg * 8;
            const float* wb = W + (size_t)(jbase + r) * 1024 + k0 + kg * 8;
            float4 a0 = *(const float4*)(xa);
            float4 a1 = *(const float4*)(xa + 4);
            float4 b0 = *(const float4*)(wb);
            float4 b1 = *(const float4*)(wb + 4);
            union { short8_t v; ushort u[8]; } ua, ub;
            float af[8] = {a0.x,a0.y,a0.z,a0.w,a1.x,a1.y,a1.z,a1.w};
            float bf[8] = {b0.x,b0.y,b0.z,b0.w,b1.x,b1.y,b1.z,b1.w};
#pragma unroll
            for (int e = 0; e < 8; ++e) {
                __hip_bfloat16 ha = __float2bfloat16(af[e]);
                __hip_bfloat16 hb = __float2bfloat16(bf[e]);
                ua.u[e] = *reinterpret_cast<ushort*>(&ha);
                ub.u[e] = *reinterpret_cast<ushort*>(&hb);
            }
            As[kg * 128 + r] = ua.v;
            Bs[kg * 128 + r] = ub.v;
        }
        __syncthreads();

        short8_t a[4], b[4];
#pragma unroll
        for (int mi = 0; mi < 4; ++mi)
            a[mi] = As[q * 128 + wm * 64 + mi * 16 + lr];
#pragma unroll
        for (int nj = 0; nj < 4; ++nj)
            b[nj] = Bs[q * 128 + wn * 64 + nj * 16 + lr];
#pragma unroll
        for (int mi = 0; mi < 4; ++mi)
#pragma unroll
            for (int nj = 0; nj < 4; ++nj)
                acc[mi][nj] = __builtin_amdgcn_mfma_f32_16x16x32_bf16(
                    a[mi], b[nj], acc[mi][nj], 0, 0, 0);
        __syncthreads();
    }

#pragma unroll
    for (int mi = 0; mi < 4; ++mi)
#pragma unroll
        for (int nj = 0; nj < 4; ++nj)
#pragma unroll
            for (int r = 0; r < 4; ++r) {
                int m = m0 + wm * 64 + mi * 16 + q * 4 + r;
                int n = bn * 128 + wn * 64 + nj * 16 + lr;
                xpb[(size_t)m * 4096 + n] = __float2bfloat16(acc[mi][nj][r]);
            }
}

// ---------------------------------------------------------------------------
// Lightweight grid barrier: monotone counter, agent scope, thread0 spins.
// ---------------------------------------------------------------------------
__device__ __forceinline__ void grid_bar(unsigned* bar, unsigned target)
{
    __syncthreads();
    if (threadIdx.x == 0) {
        __hip_atomic_fetch_add(bar, 1u, __ATOMIC_ACQ_REL, __HIP_MEMORY_SCOPE_AGENT);
        while (__hip_atomic_load(bar, __ATOMIC_ACQUIRE, __HIP_MEMORY_SCOPE_AGENT) < target)
            __builtin_amdgcn_s_sleep(1);
    }
    __syncthreads();
}

// ---------------------------------------------------------------------------
// Persistent LSTM loop, custom barrier, merged gate+out pass.
// 256 blocks x 512 thr. Block ng owns j in {4ng..4ng+3}. Wave kq: 128 k's.
// Iteration t: reads hcur=h_t -> gate partials (-> h_{t+1}) AND out partials
// for out[t-1] (= h_t @ Wout^T). Epilogue computes out[255].
// ---------------------------------------------------------------------------
template<int XFOLD>
__global__ __launch_bounds__(512, 1) void lstm_loop3(
    const __hip_bfloat16* __restrict__ xp,   // [T][64][4096] bf16
    const float* __restrict__ x,             // [T][64][1024] (XFOLD=1)
    const float* __restrict__ PWb,           // [256][1024][16]
    const float* __restrict__ PXb,           // (XFOLD=1)
    const float* __restrict__ POb,           // [256][1024][4]
    const float* __restrict__ c0,
    float* __restrict__ hb0,
    float* __restrict__ hb1,
    float* __restrict__ out,
    unsigned* __restrict__ bar)
{
    __shared__ float WL[1024 * 16];          // 64 KB
    __shared__ float OL[1024 * 4];           // 16 KB
    __shared__ float red[8 * 64 * 21];       // 42 KB (20 payload + pad)

    const int tid  = threadIdx.x;
    const int lane = tid & 63;               // b
    const int kq   = tid >> 6;               // 0..7
    const int ng   = blockIdx.x;             // 0..255

    {
        const float4* srcW = (const float4*)(PWb + (size_t)ng * 16384);
        float4* dstW = (float4*)WL;
        for (int i = tid; i < 4096; i += 512) dstW[i] = srcW[i];
        const float4* srcO = (const float4*)(POb + (size_t)ng * 4096);
        float4* dstO = (float4*)OL;
        for (int i = tid; i < 1024; i += 512) dstO[i] = srcO[i];
    }
    float c_reg = 0.f;
    if (tid < 256) c_reg = c0[(size_t)(tid >> 2) * 1024 + 4 * ng + (tid & 3)];
    __syncthreads();

    const f32x4* WL4 = (const f32x4*)WL;
    const f32x4* OL4 = (const f32x4*)OL;

    // prefetch xp for t=0
    float xpv[4] = {0.f, 0.f, 0.f, 0.f};
    if (XFOLD == 0 && tid < 256) {
        int b = tid >> 2, jj = tid & 3;
        size_t base = (size_t)b * 4096 + 4 * ng + jj;
        xpv[0] = __bfloat162float(xp[base + 0 * 1024]);
        xpv[1] = __bfloat162float(xp[base + 1 * 1024]);
        xpv[2] = __bfloat162float(xp[base + 2 * 1024]);
        xpv[3] = __bfloat162float(xp[base + 3 * 1024]);
    }

    for (int t = 0; t < T_STEPS; ++t) {
        const float* hcur = (t & 1) ? hb1 : hb0;
        float*       hnxt = (t & 1) ? hb0 : hb1;

        // ---- merged pass over hcur: 16 gate partials + 4 out partials ----
        float acc[16];
#pragma unroll
        for (int i = 0; i < 16; ++i) acc[i] = 0.f;
        float ao[4] = {0.f, 0.f, 0.f, 0.f};

        {
            const int k0 = kq * 128;
#pragma unroll 2
            for (int k = k0; k < k0 + 128; ++k) {
                float hv = hcur[k * 64 + lane];
                f32x4 w0 = WL4[k * 4 + 0];
                f32x4 w1 = WL4[k * 4 + 1];
                f32x4 w2 = WL4[k * 4 + 2];
                f32x4 w3 = WL4[k * 4 + 3];
                f32x4 wo = OL4[k];
                acc[0]  += w0[0] * hv; acc[1]  += w0[1] * hv;
                acc[2]  += w0[2] * hv; acc[3]  += w0[3] * hv;
                acc[4]  += w1[0] * hv; acc[5]  += w1[1] * hv;
                acc[6]  += w1[2] * hv; acc[7]  += w1[3] * hv;
                acc[8]  += w2[0] * hv; acc[9]  += w2[1] * hv;
                acc[10] += w2[2] * hv; acc[11] += w2[3] * hv;
                acc[12] += w3[0] * hv; acc[13] += w3[1] * hv;
                acc[14] += w3[2] * hv; acc[15] += w3[3] * hv;
                ao[0] += wo[0] * hv; ao[1] += wo[1] * hv;
                ao[2] += wo[2] * hv; ao[3] += wo[3] * hv;
                if (XFOLD == 1) {
                    float xv = x[((size_t)t * 64 + lane) * 1024 + k];
                    const f32x4* PX4 = (const f32x4*)(PXb + (size_t)ng * 16384);
                    f32x4 u0 = PX4[k * 4 + 0];
                    f32x4 u1 = PX4[k * 4 + 1];
                    f32x4 u2 = PX4[k * 4 + 2];
                    f32x4 u3 = PX4[k * 4 + 3];
                    acc[0]  += u0[0] * xv; acc[1]  += u0[1] * xv;
                    acc[2]  += u0[2] * xv; acc[3]  += u0[3] * xv;
                    acc[4]  += u1[0] * xv; acc[5]  += u1[1] * xv;
                    acc[6]  += u1[2] * xv; acc[7]  += u1[3] * xv;
                    acc[8]  += u2[0] * xv; acc[9]  += u2[1] * xv;
                    acc[10] += u2[2] * xv; acc[11] += u2[3] * xv;
                    acc[12] += u3[0] * xv; acc[13] += u3[1] * xv;
                    acc[14] += u3[2] * xv; acc[15] += u3[3] * xv;
                }
            }
        }
        {
            float* r = &red[(kq * 64 + lane) * 21];
#pragma unroll
            for (int i = 0; i < 16; ++i) r[i] = acc[i];
#pragma unroll
            for (int i = 0; i < 4; ++i) r[16 + i] = ao[i];
        }
        __syncthreads();

        // ---- combine: gates -> c,h ; write out[t-1] ----
        if (tid < 256) {
            int b = tid >> 2, jj = tid & 3;
            float pre[4];
#pragma unroll
            for (int g = 0; g < 4; ++g) {
                float s = 0.f;
#pragma unroll
                for (int qq = 0; qq < 8; ++qq)
                    s += red[(qq * 64 + b) * 21 + g * 4 + jj];
                pre[g] = s + xpv[g];
            }
            float aout = 0.f;
#pragma unroll
            for (int qq = 0; qq < 8; ++qq)
                aout += red[(qq * 64 + b) * 21 + 16 + jj];

            float gi = 1.f / (1.f + expf(-pre[0]));
            float gf = 1.f / (1.f + expf(-pre[1]));
            float go = 1.f / (1.f + expf(-pre[2]));
            float cn = gf * c_reg + gi * tanhf(pre[3]);
            c_reg = cn;
            hnxt[(4 * ng + jj) * 64 + b] = go * tanhf(cn);
            if (t > 0)
                out[(size_t)(t - 1) * 65536 + b * 1024 + 4 * ng + jj] = aout;

            // prefetch next step's xp (constant data; safe across barrier)
            if (XFOLD == 0 && t + 1 < T_STEPS) {
                size_t base = ((size_t)(t + 1) * 64 + b) * 4096 + 4 * ng + jj;
                xpv[0] = __bfloat162float(xp[base + 0 * 1024]);
                xpv[1] = __bfloat162float(xp[base + 1 * 1024]);
                xpv[2] = __bfloat162float(xp[base + 2 * 1024]);
                xpv[3] = __bfloat162float(xp[base + 3 * 1024]);
            }
        }

        grid_bar(bar, 256u * (t + 1));
    }

    // ---- epilogue: out[255] = h_256 @ Wout^T ----
    {
        const float* hcur = hb0;   // t=256 even -> hb0 holds h_256
        float ao[4] = {0.f, 0.f, 0.f, 0.f};
        const int k0 = kq * 128;
#pragma unroll 2
        for (int k = k0; k < k0 + 128; ++k) {
            float hv = hcur[k * 64 + lane];
            f32x4 wo = OL4[k];
            ao[0] += wo[0] * hv; ao[1] += wo[1] * hv;
            ao[2] += wo[2] * hv; ao[3] += wo[3] * hv;
        }
        float* r = &red[(kq * 64 + lane) * 21];
#pragma unroll
        for (int i = 0; i < 4; ++i) r[16 + i] = ao[i];
        __syncthreads();
        if (tid < 256) {
            int b = tid >> 2, jj = tid & 3;
            float aout = 0.f;
#pragma unroll
            for (int qq = 0; qq < 8; ++qq)
                aout += red[(qq * 64 + b) * 21 + 16 + jj];
            out[(size_t)255 * 65536 + b * 1024 + 4 * ng + jj] = aout;
        }
    }
}

// ---------------------------------------------------------------------------
extern "C" void kernel_launch(void* const* d_in, const int* in_sizes, int n_in,
                              void* d_out, int out_size, void* d_ws, size_t ws_size,
                              hipStream_t stream)
{
    const float* x   = (const float*)d_in[0];
    const float* h0  = (const float*)d_in[1];
    const float* c0  = (const float*)d_in[2];
    const float* Wxi = (const float*)d_in[3];
    const float* Wxf = (const float*)d_in[4];
    const float* Wxo = (const float*)d_in[5];
    const float* Wxc = (const float*)d_in[6];
    const float* Whi = (const float*)d_in[7];
    const float* Whf = (const float*)d_in[8];
    const float* Who = (const float*)d_in[9];
    const float* Whc = (const float*)d_in[10];
    const float* Wout = (const float*)d_in[11];
    float* out = (float*)d_out;

    const size_t PW_BYTES  = (size_t)256 * 1024 * 16 * 4;        // 16 MB
    const size_t PO_BYTES  = (size_t)256 * 1024 * 4 * 4;         //  4 MB
    const size_t HB_BYTES  = (size_t)1024 * 64 * 4;              // 256 KB
    const size_t BAR_BYTES = 4096;
    const size_t XPB_BYTES = (size_t)T_STEPS * 64 * 4096 * 2;    // 128 MB

    char* ws = (char*)d_ws;
    float* PWb = (float*)ws;                 ws += PW_BYTES;
    float* POb = (float*)ws;                 ws += PO_BYTES;
    float* hb0 = (float*)ws;                 ws += HB_BYTES;
    float* hb1 = (float*)ws;                 ws += HB_BYTES;
    unsigned* bar = (unsigned*)ws;           ws += BAR_BYTES;

    const size_t base_need = PW_BYTES + PO_BYTES + 2 * HB_BYTES + BAR_BYTES;
    bool use_xp = ws_size >= base_need + XPB_BYTES;

    __hip_bfloat16* xpb = nullptr;
    float* PXb = nullptr;
    if (use_xp) xpb = (__hip_bfloat16*)ws;
    else        PXb = (float*)ws;

    hipMemsetAsync(bar, 0, 256, stream);
    pack4<<<dim3(32, 32, 4), 256, 0, stream>>>(Whi, Whf, Who, Whc, PWb);
    pack_wo<<<dim3(32, 32), 256, 0, stream>>>(Wout, POb);
    transpose_h0<<<256, 256, 0, stream>>>(h0, hb0);

    if (use_xp) {
        xproj_mfma<<<dim3(128, 32), 256, 0, stream>>>(x, Wxi, Wxf, Wxo, Wxc, xpb);
    } else {
        pack4<<<dim3(32, 32, 4), 256, 0, stream>>>(Wxi, Wxf, Wxo, Wxc, PXb);
    }

    if (use_xp)
        lstm_loop3<0><<<dim3(256), dim3(512), 0, stream>>>(
            xpb, x, PWb, PXb, POb, c0, hb0, hb1, out, bar);
    else
        lstm_loop3<1><<<dim3(256), dim3(512), 0, stream>>>(
            xpb, x, PWb, PXb, POb, c0, hb0, hb1, out, bar);
}

// Round 5
// 7576.932 us; speedup vs baseline: 8.9085x; 1.0216x over previous
//
#include <hip/hip_runtime.h>
#include <hip/hip_bf16.h>
#include <math.h>

#define T_STEPS 256

typedef __attribute__((ext_vector_type(8))) short short8_t;   // 8 bf16
typedef __attribute__((ext_vector_type(4))) float f32x4;
typedef __attribute__((ext_vector_type(4))) unsigned short ushort4_t;

__device__ __forceinline__ unsigned short f2bf(float v) {
    __hip_bfloat16 h = __float2bfloat16(v);
    return *reinterpret_cast<unsigned short*>(&h);
}
__device__ __forceinline__ float bf2f(unsigned short u) {
    __hip_bfloat16 h;
    *reinterpret_cast<unsigned short*>(&h) = u;
    return __bfloat162float(h);
}

// ---------------------------------------------------------------------------
// pack_gate: gate-weight B-fragments, bf16 hi/lo split.
// PG[(ng*32+ks)*64+lane][e] = Wg[4ng+jj][ks*32+(lane>>4)*8+e], n=lane&15=g*4+jj
// grid (8, 256), block 256.
// ---------------------------------------------------------------------------
__global__ __launch_bounds__(256) void pack_gate(
    const float* __restrict__ Wi, const float* __restrict__ Wf,
    const float* __restrict__ Wo, const float* __restrict__ Wc,
    unsigned short* __restrict__ PGh, unsigned short* __restrict__ PGl)
{
    int ng = blockIdx.y;
    int ks = blockIdx.x * 4 + (threadIdx.x >> 6);
    int lane = threadIdx.x & 63;
    int n = lane & 15, g = n >> 2, jj = n & 3;
    int j = 4 * ng + jj;
    int k0 = ks * 32 + (lane >> 4) * 8;
    const float* W = (g == 0) ? Wi : (g == 1) ? Wf : (g == 2) ? Wo : Wc;
    const float* src = W + (size_t)j * 1024 + k0;

    union { short8_t v; unsigned short u[8]; } hi, lo;
#pragma unroll
    for (int e = 0; e < 8; ++e) {
        float v = src[e];
        hi.u[e] = f2bf(v);
        lo.u[e] = f2bf(v - bf2f(hi.u[e]));
    }
    size_t o = ((size_t)(ng * 32 + ks) * 64 + lane) * 8;
    *(short8_t*)(PGh + o) = hi.v;
    *(short8_t*)(PGl + o) = lo.v;
}

// ---------------------------------------------------------------------------
// pack_out: Wout B-fragments (compact: only the 4 real cols per block).
// PO[(ng*32+ks)*16 + kb*4+n][e] = Wout[4ng+n][ks*32+kb*8+e]
// grid (2, 256), block 256.
// ---------------------------------------------------------------------------
__global__ __launch_bounds__(256) void pack_out(
    const float* __restrict__ Wout,
    unsigned short* __restrict__ POh, unsigned short* __restrict__ POl)
{
    int ng = blockIdx.y;
    int ks = blockIdx.x * 16 + (threadIdx.x >> 4);
    int sl = threadIdx.x & 15;
    int kb = sl >> 2, n = sl & 3;
    int j = 4 * ng + n;
    int k0 = ks * 32 + kb * 8;
    const float* src = Wout + (size_t)j * 1024 + k0;

    union { short8_t v; unsigned short u[8]; } hi, lo;
#pragma unroll
    for (int e = 0; e < 8; ++e) {
        float v = src[e];
        hi.u[e] = f2bf(v);
        lo.u[e] = f2bf(v - bf2f(hi.u[e]));
    }
    size_t o = ((size_t)(ng * 32 + ks) * 16 + sl) * 8;
    *(short8_t*)(POh + o) = hi.v;
    *(short8_t*)(POl + o) = lo.v;
}

// ---------------------------------------------------------------------------
// trans_h0f: h0[b][k] -> A-fragment layout [copy][mt][ks][lane][8] bf16 hi/lo
// grid 64, block 256 (16384 threads, one per (copy,mt,ks,lane)).
// ---------------------------------------------------------------------------
__global__ __launch_bounds__(256) void trans_h0f(
    const float* __restrict__ h0, unsigned short* __restrict__ hA)
{
    int id = blockIdx.x * 256 + threadIdx.x;   // [0, 16384)
    int lane = id & 63;
    int ks = (id >> 6) & 31;
    int mt = (id >> 11) & 3;
    int copy = id >> 13;
    int b = mt * 16 + (lane & 15);
    int k = ks * 32 + (lane >> 4) * 8;
    const float* src = h0 + (size_t)b * 1024 + k;

    union { short8_t v; unsigned short u[8]; } o;
#pragma unroll
    for (int e = 0; e < 8; ++e) {
        float v = src[e];
        unsigned short hb = f2bf(v);
        o.u[e] = (copy == 0) ? hb : f2bf(v - bf2f(hb));
    }
    *(short8_t*)(hA + (size_t)id * 8) = o.v;
}

// ---------------------------------------------------------------------------
// xproj bf16 MFMA GEMM; epilogue scatters to xpf[t][ng][b][jj][g] bf16.
// ---------------------------------------------------------------------------
__global__ __launch_bounds__(256) void xproj_mfma(
    const float* __restrict__ X,
    const float* __restrict__ W0, const float* __restrict__ W1,
    const float* __restrict__ W2, const float* __restrict__ W3,
    unsigned short* __restrict__ xpf)
{
    __shared__ short8_t As[4 * 128];
    __shared__ short8_t Bs[4 * 128];

    const int bm = blockIdx.x;
    const int bn = blockIdx.y;
    const float* W = (bn < 8) ? W0 : (bn < 16) ? W1 : (bn < 24) ? W2 : W3;
    const int jbase = (bn & 7) * 128;
    const int m0 = bm * 128;

    const int tid  = threadIdx.x;
    const int lane = tid & 63;
    const int wave = tid >> 6;
    const int wm = wave >> 1, wn = wave & 1;
    const int q  = lane >> 4;
    const int lr = lane & 15;

    f32x4 acc[4][4];
#pragma unroll
    for (int i = 0; i < 4; ++i)
#pragma unroll
        for (int j = 0; j < 4; ++j) acc[i][j] = (f32x4){0.f, 0.f, 0.f, 0.f};

    for (int k0 = 0; k0 < 1024; k0 += 32) {
#pragma unroll
        for (int ss = 0; ss < 2; ++ss) {
            int s  = tid + ss * 256;
            int kg = s & 3, r = s >> 2;
            const float* xa = X + (size_t)(m0 + r) * 1024 + k0 + kg * 8;
            const float* wb = W + (size_t)(jbase + r) * 1024 + k0 + kg * 8;
            float4 a0 = *(const float4*)(xa);
            float4 a1 = *(const float4*)(xa + 4);
            float4 b0 = *(const float4*)(wb);
            float4 b1 = *(const float4*)(wb + 4);
            union { short8_t v; unsigned short u[8]; } ua, ub;
            float af[8] = {a0.x,a0.y,a0.z,a0.w,a1.x,a1.y,a1.z,a1.w};
            float bf[8] = {b0.x,b0.y,b0.z,b0.w,b1.x,b1.y,b1.z,b1.w};
#pragma unroll
            for (int e = 0; e < 8; ++e) {
                ua.u[e] = f2bf(af[e]);
                ub.u[e] = f2bf(bf[e]);
            }
            As[kg * 128 + r] = ua.v;
            Bs[kg * 128 + r] = ub.v;
        }
        __syncthreads();

        short8_t a[4], b[4];
#pragma unroll
        for (int mi = 0; mi < 4; ++mi)
            a[mi] = As[q * 128 + wm * 64 + mi * 16 + lr];
#pragma unroll
        for (int nj = 0; nj < 4; ++nj)
            b[nj] = Bs[q * 128 + wn * 64 + nj * 16 + lr];
#pragma unroll
        for (int mi = 0; mi < 4; ++mi)
#pragma unroll
            for (int nj = 0; nj < 4; ++nj)
                acc[mi][nj] = __builtin_amdgcn_mfma_f32_16x16x32_bf16(
                    a[mi], b[nj], acc[mi][nj], 0, 0, 0);
        __syncthreads();
    }

#pragma unroll
    for (int mi = 0; mi < 4; ++mi)
#pragma unroll
        for (int nj = 0; nj < 4; ++nj)
#pragma unroll
            for (int r = 0; r < 4; ++r) {
                int m = m0 + wm * 64 + mi * 16 + q * 4 + r;
                int n = bn * 128 + wn * 64 + nj * 16 + lr;
                int tt = m >> 6, bb = m & 63;
                int g = n >> 10, jc = n & 1023;
                xpf[(((size_t)tt * 256 + (jc >> 2)) * 64 + bb) * 16 + (jc & 3) * 4 + g]
                    = f2bf(acc[mi][nj][r]);
            }
}

// ---------------------------------------------------------------------------
// Persistent MFMA LSTM loop.
// 256 blocks x 512 thr. Block ng owns j in {4ng..4ng+3} (16 gate cols) +
// Wout cols {4ng..4ng+3}. Wave kq owns K-steps 4kq..4kq+3; B-frags in VGPRs.
// bf16x2 (hi+lo) for both weights and h: 3 MFMA passes -> ~fp32 accuracy.
// ---------------------------------------------------------------------------
__global__ __launch_bounds__(512, 1) void lstm_loop4(
    const unsigned short* __restrict__ xpf,
    const unsigned short* __restrict__ PGh, const unsigned short* __restrict__ PGl,
    const unsigned short* __restrict__ POh, const unsigned short* __restrict__ POl,
    const float* __restrict__ c0,
    unsigned short* __restrict__ hA, unsigned short* __restrict__ hB,
    float* __restrict__ out,
    unsigned* __restrict__ bar)
{
    __shared__ f32x4 red[8][8][64];    // [q][tile][lane]  64 KB
    __shared__ f32x4 redF[8][64];      // reduced tiles     8 KB
    __shared__ unsigned short hsc[64 * 2 * 4];  // h repack  1 KB

    const int tid  = threadIdx.x;
    const int lane = tid & 63;
    const int kq   = tid >> 6;
    const int ng   = blockIdx.x;

    // ---- persistent B fragments in registers ----
    short8_t bgh[4], bgl[4], boh[4], bol[4];
#pragma unroll
    for (int i = 0; i < 4; ++i) {
        int ks = 4 * kq + i;
        size_t og = ((size_t)(ng * 32 + ks) * 64 + lane) * 8;
        bgh[i] = *(const short8_t*)(PGh + og);
        bgl[i] = *(const short8_t*)(PGl + og);
        short8_t zh = {0,0,0,0,0,0,0,0};
        short8_t zl = {0,0,0,0,0,0,0,0};
        if ((lane & 15) < 4) {
            size_t oo = ((size_t)(ng * 32 + ks) * 16 + (lane >> 4) * 4 + (lane & 3)) * 8;
            zh = *(const short8_t*)(POh + oo);
            zl = *(const short8_t*)(POl + oo);
        }
        boh[i] = zh; bol[i] = zl;
    }

    const int cb = tid >> 2, cjj = tid & 3;       // combine identity (tid<256)
    float c_reg = 0.f;
    ushort4_t xq = {0, 0, 0, 0};
    if (tid < 256) {
        c_reg = c0[(size_t)cb * 1024 + 4 * ng + cjj];
        xq = *(const ushort4_t*)(xpf + ((size_t)ng * 64 + cb) * 16 + cjj * 4);
    }

    // h-store address pieces (cell for j=4ng+jj lives at fixed ks2/lane-hi/e0)
    const int ks2  = ng >> 3;
    const int l2hi = ((ng >> 1) & 3) << 4;
    const int e0   = 4 * (ng & 1);

#pragma unroll 1
    for (int t = 0; t <= T_STEPS; ++t) {
        const unsigned short* hc = (t & 1) ? hB : hA;
        unsigned short*       hn = (t & 1) ? hA : hB;

        f32x4 acc[4][2];
#pragma unroll
        for (int mt = 0; mt < 4; ++mt) {
            acc[mt][0] = (f32x4){0.f, 0.f, 0.f, 0.f};
            acc[mt][1] = (f32x4){0.f, 0.f, 0.f, 0.f};
        }

#pragma unroll
        for (int i = 0; i < 4; ++i) {
            const int ks = 4 * kq + i;
            short8_t ah[4], al[4];
#pragma unroll
            for (int mt = 0; mt < 4; ++mt) {
                int off = ((mt * 32 + ks) * 64 + lane) * 8;
                ah[mt] = *(const short8_t*)(hc + off);
                al[mt] = *(const short8_t*)(hc + 65536 + off);
            }
#pragma unroll
            for (int mt = 0; mt < 4; ++mt) {
                acc[mt][0] = __builtin_amdgcn_mfma_f32_16x16x32_bf16(ah[mt], bgh[i], acc[mt][0], 0,0,0);
                acc[mt][1] = __builtin_amdgcn_mfma_f32_16x16x32_bf16(ah[mt], boh[i], acc[mt][1], 0,0,0);
                acc[mt][0] = __builtin_amdgcn_mfma_f32_16x16x32_bf16(al[mt], bgh[i], acc[mt][0], 0,0,0);
                acc[mt][1] = __builtin_amdgcn_mfma_f32_16x16x32_bf16(al[mt], boh[i], acc[mt][1], 0,0,0);
                acc[mt][0] = __builtin_amdgcn_mfma_f32_16x16x32_bf16(ah[mt], bgl[i], acc[mt][0], 0,0,0);
                acc[mt][1] = __builtin_amdgcn_mfma_f32_16x16x32_bf16(ah[mt], bol[i], acc[mt][1], 0,0,0);
            }
        }

        // ---- K-reduction across 8 waves ----
#pragma unroll
        for (int mt = 0; mt < 4; ++mt) {
            red[kq][mt * 2 + 0][lane] = acc[mt][0];
            red[kq][mt * 2 + 1][lane] = acc[mt][1];
        }
        __syncthreads();
        {
            f32x4 s = red[0][kq][lane];
#pragma unroll
            for (int q = 1; q < 8; ++q) s += red[q][kq][lane];
            redF[kq][lane] = s;
        }
        __syncthreads();

        // ---- combine: gates -> c,h ; out[t-1] ----
        if (tid < 256) {
            const int mt = cb >> 4;
            const int ln = (cb & 12) << 2;
            const int rg = cb & 3;
            float ov = redF[mt * 2 + 1][ln | cjj][rg];
            if (t > 0)
                out[(size_t)(t - 1) * 65536 + cb * 1024 + 4 * ng + cjj] = ov;
            if (t < T_STEPS) {
                float pre0 = redF[mt * 2][ln | (0 + cjj)][rg]  + bf2f(xq[0]);
                float pre1 = redF[mt * 2][ln | (4 + cjj)][rg]  + bf2f(xq[1]);
                float pre2 = redF[mt * 2][ln | (8 + cjj)][rg]  + bf2f(xq[2]);
                float pre3 = redF[mt * 2][ln | (12 + cjj)][rg] + bf2f(xq[3]);
                float gi = 1.f / (1.f + expf(-pre0));
                float gf = 1.f / (1.f + expf(-pre1));
                float go = 1.f / (1.f + expf(-pre2));
                float cn = gf * c_reg + gi * tanhf(pre3);
                c_reg = cn;
                float hv = go * tanhf(cn);
                unsigned short hhi = f2bf(hv);
                unsigned short hlo = f2bf(hv - bf2f(hhi));
                hsc[(cb * 2 + 0) * 4 + cjj] = hhi;
                hsc[(cb * 2 + 1) * 4 + cjj] = hlo;
                if (t + 1 < T_STEPS)
                    xq = *(const ushort4_t*)(xpf +
                        (((size_t)(t + 1) * 256 + ng) * 64 + cb) * 16 + cjj * 4);
            }
        }
        __syncthreads();

        // ---- h (bf16 hi/lo) 8B stores into fragment layout ----
        if (tid < 128 && t < T_STEPS) {
            int b = tid >> 1, cp = tid & 1;
            ushort4_t v = *(const ushort4_t*)(hsc + (b * 2 + cp) * 4);
            int elem = ((cp * 4 + (b >> 4)) * 32 + ks2) * 512 + ((b & 15) | l2hi) * 8 + e0;
            *(ushort4_t*)(hn + elem) = v;
        }

        // ---- striped grid barrier ----
        if (t < T_STEPS) {
            __syncthreads();
            if (tid == 0) {
                unsigned* stripe = bar + (ng & 7) * 32;
                unsigned old = __hip_atomic_fetch_add(stripe, 1u,
                                    __ATOMIC_ACQ_REL, __HIP_MEMORY_SCOPE_AGENT);
                if (old == 32u * (t + 1) - 1u) {
                    unsigned o2 = __hip_atomic_fetch_add(bar + 256, 1u,
                                    __ATOMIC_ACQ_REL, __HIP_MEMORY_SCOPE_AGENT);
                    if (o2 == 8u * (t + 1) - 1u)
                        __hip_atomic_store(bar + 272, (unsigned)(t + 1),
                                    __ATOMIC_RELEASE, __HIP_MEMORY_SCOPE_AGENT);
                }
                while (__hip_atomic_load(bar + 272,
                            __ATOMIC_ACQUIRE, __HIP_MEMORY_SCOPE_AGENT) < (unsigned)(t + 1))
                    __builtin_amdgcn_s_sleep(1);
            }
            __syncthreads();
        }
    }
}

// ---------------------------------------------------------------------------
extern "C" void kernel_launch(void* const* d_in, const int* in_sizes, int n_in,
                              void* d_out, int out_size, void* d_ws, size_t ws_size,
                              hipStream_t stream)
{
    const float* x    = (const float*)d_in[0];
    const float* h0   = (const float*)d_in[1];
    const float* c0   = (const float*)d_in[2];
    const float* Wxi  = (const float*)d_in[3];
    const float* Wxf  = (const float*)d_in[4];
    const float* Wxo  = (const float*)d_in[5];
    const float* Wxc  = (const float*)d_in[6];
    const float* Whi  = (const float*)d_in[7];
    const float* Whf  = (const float*)d_in[8];
    const float* Who  = (const float*)d_in[9];
    const float* Whc  = (const float*)d_in[10];
    const float* Wout = (const float*)d_in[11];
    float* out = (float*)d_out;

    const size_t PG_B  = (size_t)256 * 32 * 64 * 8 * 2;     //  8,388,608
    const size_t PO_B  = (size_t)256 * 32 * 16 * 8 * 2;     //  2,097,152
    const size_t HF_B  = (size_t)2 * 4 * 32 * 64 * 8 * 2;   //    262,144
    const size_t BAR_B = 4096;
    const size_t XPF_B = (size_t)T_STEPS * 256 * 64 * 16 * 2; // 134,217,728

    char* ws = (char*)d_ws;
    unsigned short* PGh = (unsigned short*)ws;  ws += PG_B;
    unsigned short* PGl = (unsigned short*)ws;  ws += PG_B;
    unsigned short* POh = (unsigned short*)ws;  ws += PO_B;
    unsigned short* POl = (unsigned short*)ws;  ws += PO_B;
    unsigned short* hA  = (unsigned short*)ws;  ws += HF_B;
    unsigned short* hB  = (unsigned short*)ws;  ws += HF_B;
    unsigned*       bar = (unsigned*)ws;        ws += BAR_B;
    unsigned short* xpf = (unsigned short*)ws;  ws += XPF_B;

    hipMemsetAsync(bar, 0, BAR_B, stream);
    pack_gate<<<dim3(8, 256), 256, 0, stream>>>(Whi, Whf, Who, Whc, PGh, PGl);
    pack_out<<<dim3(2, 256), 256, 0, stream>>>(Wout, POh, POl);
    trans_h0f<<<dim3(64), 256, 0, stream>>>(h0, hA);
    xproj_mfma<<<dim3(128, 32), 256, 0, stream>>>(x, Wxi, Wxf, Wxo, Wxc, xpf);

    lstm_loop4<<<dim3(256), dim3(512), 0, stream>>>(
        xpf, PGh, PGl, POh, POl, c0, hA, hB, out, bar);
}

// Round 6
// 4151.162 us; speedup vs baseline: 16.2603x; 1.8253x over previous
//
#include <hip/hip_runtime.h>
#include <hip/hip_bf16.h>
#include <math.h>

#define T_STEPS 256

typedef __attribute__((ext_vector_type(8))) short short8_t;   // 8 bf16
typedef __attribute__((ext_vector_type(4))) float f32x4;
typedef __attribute__((ext_vector_type(4))) unsigned short ushort4_t;

__device__ __forceinline__ unsigned short f2bf(float v) {
    __hip_bfloat16 h = __float2bfloat16(v);
    return *reinterpret_cast<unsigned short*>(&h);
}
__device__ __forceinline__ float bf2f(unsigned short u) {
    __hip_bfloat16 h;
    *reinterpret_cast<unsigned short*>(&h) = u;
    return __bfloat162float(h);
}

// ---------------------------------------------------------------------------
// pack_gate: gate-weight B-fragments, bf16 hi/lo split.
// PG[(ng*32+ks)*64+lane][e] = Wg[4ng+jj][ks*32+(lane>>4)*8+e], n=lane&15=g*4+jj
// ---------------------------------------------------------------------------
__global__ __launch_bounds__(256) void pack_gate(
    const float* __restrict__ Wi, const float* __restrict__ Wf,
    const float* __restrict__ Wo, const float* __restrict__ Wc,
    unsigned short* __restrict__ PGh, unsigned short* __restrict__ PGl)
{
    int ng = blockIdx.y;
    int ks = blockIdx.x * 4 + (threadIdx.x >> 6);
    int lane = threadIdx.x & 63;
    int n = lane & 15, g = n >> 2, jj = n & 3;
    int j = 4 * ng + jj;
    int k0 = ks * 32 + (lane >> 4) * 8;
    const float* W = (g == 0) ? Wi : (g == 1) ? Wf : (g == 2) ? Wo : Wc;
    const float* src = W + (size_t)j * 1024 + k0;

    union { short8_t v; unsigned short u[8]; } hi, lo;
#pragma unroll
    for (int e = 0; e < 8; ++e) {
        float v = src[e];
        hi.u[e] = f2bf(v);
        lo.u[e] = f2bf(v - bf2f(hi.u[e]));
    }
    size_t o = ((size_t)(ng * 32 + ks) * 64 + lane) * 8;
    *(short8_t*)(PGh + o) = hi.v;
    *(short8_t*)(PGl + o) = lo.v;
}

// ---------------------------------------------------------------------------
// pack_out: Wout B-fragments (compact: only the 4 real cols per block).
// ---------------------------------------------------------------------------
__global__ __launch_bounds__(256) void pack_out(
    const float* __restrict__ Wout,
    unsigned short* __restrict__ POh, unsigned short* __restrict__ POl)
{
    int ng = blockIdx.y;
    int ks = blockIdx.x * 16 + (threadIdx.x >> 4);
    int sl = threadIdx.x & 15;
    int kb = sl >> 2, n = sl & 3;
    int j = 4 * ng + n;
    int k0 = ks * 32 + kb * 8;
    const float* src = Wout + (size_t)j * 1024 + k0;

    union { short8_t v; unsigned short u[8]; } hi, lo;
#pragma unroll
    for (int e = 0; e < 8; ++e) {
        float v = src[e];
        hi.u[e] = f2bf(v);
        lo.u[e] = f2bf(v - bf2f(hi.u[e]));
    }
    size_t o = ((size_t)(ng * 32 + ks) * 16 + sl) * 8;
    *(short8_t*)(POh + o) = hi.v;
    *(short8_t*)(POl + o) = lo.v;
}

// ---------------------------------------------------------------------------
// trans_h0f: h0[b][k] -> A-fragment layout [copy][mt][ks][lane][8] bf16 hi/lo
// ---------------------------------------------------------------------------
__global__ __launch_bounds__(256) void trans_h0f(
    const float* __restrict__ h0, unsigned short* __restrict__ hA)
{
    int id = blockIdx.x * 256 + threadIdx.x;   // [0, 16384)
    int lane = id & 63;
    int ks = (id >> 6) & 31;
    int mt = (id >> 11) & 3;
    int copy = id >> 13;
    int b = mt * 16 + (lane & 15);
    int k = ks * 32 + (lane >> 4) * 8;
    const float* src = h0 + (size_t)b * 1024 + k;

    union { short8_t v; unsigned short u[8]; } o;
#pragma unroll
    for (int e = 0; e < 8; ++e) {
        float v = src[e];
        unsigned short hb = f2bf(v);
        o.u[e] = (copy == 0) ? hb : f2bf(v - bf2f(hb));
    }
    *(short8_t*)(hA + (size_t)id * 8) = o.v;
}

// ---------------------------------------------------------------------------
// xproj bf16 MFMA GEMM; epilogue scatters to xpf[t][ng][b][jj][g] bf16.
// ---------------------------------------------------------------------------
__global__ __launch_bounds__(256) void xproj_mfma(
    const float* __restrict__ X,
    const float* __restrict__ W0, const float* __restrict__ W1,
    const float* __restrict__ W2, const float* __restrict__ W3,
    unsigned short* __restrict__ xpf)
{
    __shared__ short8_t As[4 * 128];
    __shared__ short8_t Bs[4 * 128];

    const int bm = blockIdx.x;
    const int bn = blockIdx.y;
    const float* W = (bn < 8) ? W0 : (bn < 16) ? W1 : (bn < 24) ? W2 : W3;
    const int jbase = (bn & 7) * 128;
    const int m0 = bm * 128;

    const int tid  = threadIdx.x;
    const int lane = tid & 63;
    const int wave = tid >> 6;
    const int wm = wave >> 1, wn = wave & 1;
    const int q  = lane >> 4;
    const int lr = lane & 15;

    f32x4 acc[4][4];
#pragma unroll
    for (int i = 0; i < 4; ++i)
#pragma unroll
        for (int j = 0; j < 4; ++j) acc[i][j] = (f32x4){0.f, 0.f, 0.f, 0.f};

    for (int k0 = 0; k0 < 1024; k0 += 32) {
#pragma unroll
        for (int ss = 0; ss < 2; ++ss) {
            int s  = tid + ss * 256;
            int kg = s & 3, r = s >> 2;
            const float* xa = X + (size_t)(m0 + r) * 1024 + k0 + kg * 8;
            const float* wb = W + (size_t)(jbase + r) * 1024 + k0 + kg * 8;
            float4 a0 = *(const float4*)(xa);
            float4 a1 = *(const float4*)(xa + 4);
            float4 b0 = *(const float4*)(wb);
            float4 b1 = *(const float4*)(wb + 4);
            union { short8_t v; unsigned short u[8]; } ua, ub;
            float af[8] = {a0.x,a0.y,a0.z,a0.w,a1.x,a1.y,a1.z,a1.w};
            float bf[8] = {b0.x,b0.y,b0.z,b0.w,b1.x,b1.y,b1.z,b1.w};
#pragma unroll
            for (int e = 0; e < 8; ++e) {
                ua.u[e] = f2bf(af[e]);
                ub.u[e] = f2bf(bf[e]);
            }
            As[kg * 128 + r] = ua.v;
            Bs[kg * 128 + r] = ub.v;
        }
        __syncthreads();

        short8_t a[4], b[4];
#pragma unroll
        for (int mi = 0; mi < 4; ++mi)
            a[mi] = As[q * 128 + wm * 64 + mi * 16 + lr];
#pragma unroll
        for (int nj = 0; nj < 4; ++nj)
            b[nj] = Bs[q * 128 + wn * 64 + nj * 16 + lr];
#pragma unroll
        for (int mi = 0; mi < 4; ++mi)
#pragma unroll
            for (int nj = 0; nj < 4; ++nj)
                acc[mi][nj] = __builtin_amdgcn_mfma_f32_16x16x32_bf16(
                    a[mi], b[nj], acc[mi][nj], 0, 0, 0);
        __syncthreads();
    }

#pragma unroll
    for (int mi = 0; mi < 4; ++mi)
#pragma unroll
        for (int nj = 0; nj < 4; ++nj)
#pragma unroll
            for (int r = 0; r < 4; ++r) {
                int m = m0 + wm * 64 + mi * 16 + q * 4 + r;
                int n = bn * 128 + wn * 64 + nj * 16 + lr;
                int tt = m >> 6, bb = m & 63;
                int g = n >> 10, jc = n & 1023;
                xpf[(((size_t)tt * 256 + (jc >> 2)) * 64 + bb) * 16 + (jc & 3) * 4 + g]
                    = f2bf(acc[mi][nj][r]);
            }
}

// ---------------------------------------------------------------------------
// Persistent MFMA LSTM loop — L3-bypass communication, no cache-wide fences.
// h exchanged via SYSTEM-scope relaxed 8B atomics (sc0 sc1: straight to the
// memory-side Infinity Cache, visible to all XCDs without L2 wb/inv).
// Barrier: relaxed SYSTEM fetch_add arrivals after an explicit vmcnt drain;
// block0 aggregates; relaxed SYSTEM flag polls. No ACQUIRE invalidates.
// ---------------------------------------------------------------------------
__global__ __launch_bounds__(512, 1) void lstm_loop5(
    const unsigned short* __restrict__ xpf,
    const unsigned short* __restrict__ PGh, const unsigned short* __restrict__ PGl,
    const unsigned short* __restrict__ POh, const unsigned short* __restrict__ POl,
    const float* __restrict__ c0,
    unsigned short* __restrict__ hA, unsigned short* __restrict__ hB,
    float* __restrict__ out,
    unsigned* __restrict__ bar)
{
    __shared__ f32x4 red[8][8][64];    // [q][tile][lane]  64 KB
    __shared__ f32x4 redF[8][64];      // reduced tiles     8 KB
    __shared__ unsigned short hsc[64 * 2 * 4];  // h repack  1 KB

    const int tid  = threadIdx.x;
    const int lane = tid & 63;
    const int kq   = tid >> 6;
    const int ng   = blockIdx.x;

    unsigned* cnt  = bar;        // arrival counter (own 128B line)
    unsigned* flag = bar + 64;   // epoch flag      (own 128B line)

    // ---- persistent B fragments in registers ----
    short8_t bgh[4], bgl[4], boh[4], bol[4];
#pragma unroll
    for (int i = 0; i < 4; ++i) {
        int ks = 4 * kq + i;
        size_t og = ((size_t)(ng * 32 + ks) * 64 + lane) * 8;
        bgh[i] = *(const short8_t*)(PGh + og);
        bgl[i] = *(const short8_t*)(PGl + og);
        short8_t zh = {0,0,0,0,0,0,0,0};
        short8_t zl = {0,0,0,0,0,0,0,0};
        if ((lane & 15) < 4) {
            size_t oo = ((size_t)(ng * 32 + ks) * 16 + (lane >> 4) * 4 + (lane & 3)) * 8;
            zh = *(const short8_t*)(POh + oo);
            zl = *(const short8_t*)(POl + oo);
        }
        boh[i] = zh; bol[i] = zl;
    }

    const int cb = tid >> 2, cjj = tid & 3;       // combine identity (tid<256)
    float c_reg = 0.f;
    ushort4_t xq = {0, 0, 0, 0};
    if (tid < 256) {
        c_reg = c0[(size_t)cb * 1024 + 4 * ng + cjj];
        xq = *(const ushort4_t*)(xpf + ((size_t)ng * 64 + cb) * 16 + cjj * 4);
    }

    // h-store address pieces
    const int ks2  = ng >> 3;
    const int l2hi = ((ng >> 1) & 3) << 4;
    const int e0   = 4 * (ng & 1);

#pragma unroll 1
    for (int t = 0; t <= T_STEPS; ++t) {
        const unsigned short* hc = (t & 1) ? hB : hA;
        unsigned short*       hn = (t & 1) ? hA : hB;

        f32x4 acc[4][2];
#pragma unroll
        for (int mt = 0; mt < 4; ++mt) {
            acc[mt][0] = (f32x4){0.f, 0.f, 0.f, 0.f};
            acc[mt][1] = (f32x4){0.f, 0.f, 0.f, 0.f};
        }

#pragma unroll
        for (int i = 0; i < 4; ++i) {
            const int ks = 4 * kq + i;
            short8_t ah[4], al[4];
#pragma unroll
            for (int mt = 0; mt < 4; ++mt) {
                int off = ((mt * 32 + ks) * 64 + lane) * 8;
                union { short8_t v; unsigned long long q[2]; } uh, ul;
                const unsigned long long* ph = (const unsigned long long*)(hc + off);
                const unsigned long long* pl = (const unsigned long long*)(hc + 65536 + off);
                uh.q[0] = __hip_atomic_load(ph,     __ATOMIC_RELAXED, __HIP_MEMORY_SCOPE_SYSTEM);
                uh.q[1] = __hip_atomic_load(ph + 1, __ATOMIC_RELAXED, __HIP_MEMORY_SCOPE_SYSTEM);
                ul.q[0] = __hip_atomic_load(pl,     __ATOMIC_RELAXED, __HIP_MEMORY_SCOPE_SYSTEM);
                ul.q[1] = __hip_atomic_load(pl + 1, __ATOMIC_RELAXED, __HIP_MEMORY_SCOPE_SYSTEM);
                ah[mt] = uh.v;
                al[mt] = ul.v;
            }
#pragma unroll
            for (int mt = 0; mt < 4; ++mt) {
                acc[mt][0] = __builtin_amdgcn_mfma_f32_16x16x32_bf16(ah[mt], bgh[i], acc[mt][0], 0,0,0);
                acc[mt][1] = __builtin_amdgcn_mfma_f32_16x16x32_bf16(ah[mt], boh[i], acc[mt][1], 0,0,0);
                acc[mt][0] = __builtin_amdgcn_mfma_f32_16x16x32_bf16(al[mt], bgh[i], acc[mt][0], 0,0,0);
                acc[mt][1] = __builtin_amdgcn_mfma_f32_16x16x32_bf16(al[mt], boh[i], acc[mt][1], 0,0,0);
                acc[mt][0] = __builtin_amdgcn_mfma_f32_16x16x32_bf16(ah[mt], bgl[i], acc[mt][0], 0,0,0);
                acc[mt][1] = __builtin_amdgcn_mfma_f32_16x16x32_bf16(ah[mt], bol[i], acc[mt][1], 0,0,0);
            }
        }

        // ---- K-reduction across 8 waves ----
#pragma unroll
        for (int mt = 0; mt < 4; ++mt) {
            red[kq][mt * 2 + 0][lane] = acc[mt][0];
            red[kq][mt * 2 + 1][lane] = acc[mt][1];
        }
        __syncthreads();
        {
            f32x4 s = red[0][kq][lane];
#pragma unroll
            for (int q = 1; q < 8; ++q) s += red[q][kq][lane];
            redF[kq][lane] = s;
        }
        __syncthreads();

        // ---- combine: gates -> c,h ; out[t-1] ----
        if (tid < 256) {
            const int mt = cb >> 4;
            const int ln = (cb & 12) << 2;
            const int rg = cb & 3;
            float ov = redF[mt * 2 + 1][ln | cjj][rg];
            if (t > 0)
                out[(size_t)(t - 1) * 65536 + cb * 1024 + 4 * ng + cjj] = ov;
            if (t < T_STEPS) {
                float pre0 = redF[mt * 2][ln | (0 + cjj)][rg]  + bf2f(xq[0]);
                float pre1 = redF[mt * 2][ln | (4 + cjj)][rg]  + bf2f(xq[1]);
                float pre2 = redF[mt * 2][ln | (8 + cjj)][rg]  + bf2f(xq[2]);
                float pre3 = redF[mt * 2][ln | (12 + cjj)][rg] + bf2f(xq[3]);
                float gi = 1.f / (1.f + expf(-pre0));
                float gf = 1.f / (1.f + expf(-pre1));
                float go = 1.f / (1.f + expf(-pre2));
                float cn = gf * c_reg + gi * tanhf(pre3);
                c_reg = cn;
                float hv = go * tanhf(cn);
                unsigned short hhi = f2bf(hv);
                unsigned short hlo = f2bf(hv - bf2f(hhi));
                hsc[(cb * 2 + 0) * 4 + cjj] = hhi;
                hsc[(cb * 2 + 1) * 4 + cjj] = hlo;
                if (t + 1 < T_STEPS)
                    xq = *(const ushort4_t*)(xpf +
                        (((size_t)(t + 1) * 256 + ng) * 64 + cb) * 16 + cjj * 4);
            }
        }
        __syncthreads();

        // ---- h (bf16 hi/lo) 8B bypass stores (straight to L3) ----
        if (tid < 128 && t < T_STEPS) {
            int b = tid >> 1, cp = tid & 1;
            union { ushort4_t v4; unsigned long long q; } u;
            u.v4 = *(const ushort4_t*)(hsc + (b * 2 + cp) * 4);
            int elem = ((cp * 4 + (b >> 4)) * 32 + ks2) * 512 + ((b & 15) | l2hi) * 8 + e0;
            __hip_atomic_store((unsigned long long*)(hn + elem), u.q,
                               __ATOMIC_RELAXED, __HIP_MEMORY_SCOPE_SYSTEM);
        }

        // ---- grid barrier: relaxed SYSTEM protocol, no cache invalidates ----
        if (t < T_STEPS) {
            __syncthreads();
            if (tid == 0) {
                asm volatile("s_waitcnt vmcnt(0)" ::: "memory");
                __hip_atomic_fetch_add(cnt, 1u, __ATOMIC_RELAXED, __HIP_MEMORY_SCOPE_SYSTEM);
                unsigned tgt = (unsigned)(t + 1);
                if (ng == 0) {
                    while (__hip_atomic_load(cnt, __ATOMIC_RELAXED, __HIP_MEMORY_SCOPE_SYSTEM) < 256u * tgt)
                        __builtin_amdgcn_s_sleep(1);
                    __hip_atomic_store(flag, tgt, __ATOMIC_RELAXED, __HIP_MEMORY_SCOPE_SYSTEM);
                } else {
                    while (__hip_atomic_load(flag, __ATOMIC_RELAXED, __HIP_MEMORY_SCOPE_SYSTEM) < tgt)
                        __builtin_amdgcn_s_sleep(1);
                }
            }
            __syncthreads();
        }
    }
}

// ---------------------------------------------------------------------------
extern "C" void kernel_launch(void* const* d_in, const int* in_sizes, int n_in,
                              void* d_out, int out_size, void* d_ws, size_t ws_size,
                              hipStream_t stream)
{
    const float* x    = (const float*)d_in[0];
    const float* h0   = (const float*)d_in[1];
    const float* c0   = (const float*)d_in[2];
    const float* Wxi  = (const float*)d_in[3];
    const float* Wxf  = (const float*)d_in[4];
    const float* Wxo  = (const float*)d_in[5];
    const float* Wxc  = (const float*)d_in[6];
    const float* Whi  = (const float*)d_in[7];
    const float* Whf  = (const float*)d_in[8];
    const float* Who  = (const float*)d_in[9];
    const float* Whc  = (const float*)d_in[10];
    const float* Wout = (const float*)d_in[11];
    float* out = (float*)d_out;

    const size_t PG_B  = (size_t)256 * 32 * 64 * 8 * 2;     //  8,388,608
    const size_t PO_B  = (size_t)256 * 32 * 16 * 8 * 2;     //  2,097,152
    const size_t HF_B  = (size_t)2 * 4 * 32 * 64 * 8 * 2;   //    262,144
    const size_t BAR_B = 4096;
    const size_t XPF_B = (size_t)T_STEPS * 256 * 64 * 16 * 2; // 134,217,728

    char* ws = (char*)d_ws;
    unsigned short* PGh = (unsigned short*)ws;  ws += PG_B;
    unsigned short* PGl = (unsigned short*)ws;  ws += PG_B;
    unsigned short* POh = (unsigned short*)ws;  ws += PO_B;
    unsigned short* POl = (unsigned short*)ws;  ws += PO_B;
    unsigned short* hA  = (unsigned short*)ws;  ws += HF_B;
    unsigned short* hB  = (unsigned short*)ws;  ws += HF_B;
    unsigned*       bar = (unsigned*)ws;        ws += BAR_B;
    unsigned short* xpf = (unsigned short*)ws;  ws += XPF_B;

    hipMemsetAsync(bar, 0, BAR_B, stream);
    pack_gate<<<dim3(8, 256), 256, 0, stream>>>(Whi, Whf, Who, Whc, PGh, PGl);
    pack_out<<<dim3(2, 256), 256, 0, stream>>>(Wout, POh, POl);
    trans_h0f<<<dim3(64), 256, 0, stream>>>(h0, hA);
    xproj_mfma<<<dim3(128, 32), 256, 0, stream>>>(x, Wxi, Wxf, Wxo, Wxc, xpf);

    lstm_loop5<<<dim3(256), dim3(512), 0, stream>>>(
        xpf, PGh, PGl, POh, POl, c0, hA, hB, out, bar);
}

// Round 7
// 3629.833 us; speedup vs baseline: 18.5956x; 1.1436x over previous
//
#include <hip/hip_runtime.h>
#include <hip/hip_bf16.h>
#include <math.h>

#define T_STEPS 256
#define NBLK    128

typedef __attribute__((ext_vector_type(8))) short short8_t;   // 8 bf16
typedef __attribute__((ext_vector_type(4))) float f32x4;
typedef __attribute__((ext_vector_type(4))) unsigned short ushort4_t;

__device__ __forceinline__ unsigned short f2bf(float v) {
    __hip_bfloat16 h = __float2bfloat16(v);
    return *reinterpret_cast<unsigned short*>(&h);
}
__device__ __forceinline__ float bf2f(unsigned short u) {
    __hip_bfloat16 h;
    *reinterpret_cast<unsigned short*>(&h) = u;
    return __bfloat162float(h);
}

// ---------------------------------------------------------------------------
// pack_gate: gate-weight B-fragments for 128-block layout, bf16 hi/lo.
// Block ng owns j in [8ng, 8ng+8): 2 n-tiles (nt). Within tile nt, col
// n = lane&15 -> g = n>>2, j = 8ng + nt*4 + (n&3); k = ks*32+(lane>>4)*8+e.
// dst[(((ng*2+nt)*32+ks)*64+lane)*8 + e]
// grid (16, 128), block 256: slot = bx*4 + (tid>>6) = nt*32+ks.
// ---------------------------------------------------------------------------
__global__ __launch_bounds__(256) void pack_gate(
    const float* __restrict__ Wi, const float* __restrict__ Wf,
    const float* __restrict__ Wo, const float* __restrict__ Wc,
    unsigned short* __restrict__ PGh, unsigned short* __restrict__ PGl)
{
    int ng = blockIdx.y;
    int slot = blockIdx.x * 4 + (threadIdx.x >> 6);   // 0..63
    int nt = slot >> 5, ks = slot & 31;
    int lane = threadIdx.x & 63;
    int n = lane & 15, g = n >> 2;
    int j = 8 * ng + nt * 4 + (n & 3);
    int k0 = ks * 32 + (lane >> 4) * 8;
    const float* W = (g == 0) ? Wi : (g == 1) ? Wf : (g == 2) ? Wo : Wc;
    const float* src = W + (size_t)j * 1024 + k0;

    union { short8_t v; unsigned short u[8]; } hi, lo;
#pragma unroll
    for (int e = 0; e < 8; ++e) {
        float v = src[e];
        hi.u[e] = f2bf(v);
        lo.u[e] = f2bf(v - bf2f(hi.u[e]));
    }
    size_t o = (((size_t)(ng * 2 + nt) * 32 + ks) * 64 + lane) * 8;
    *(short8_t*)(PGh + o) = hi.v;
    *(short8_t*)(PGl + o) = lo.v;
}

// ---------------------------------------------------------------------------
// pack_out: compact out-weight frags (8 real cols per block).
// dst[((ng*32+ks)*32 + kb*8 + n)*8 + e] = Wout[8ng+n][ks*32+kb*8+e]
// grid (4, 128), block 256: ks = bx*8 + tid>>5; sl = tid&31.
// ---------------------------------------------------------------------------
__global__ __launch_bounds__(256) void pack_out(
    const float* __restrict__ Wout,
    unsigned short* __restrict__ POh, unsigned short* __restrict__ POl)
{
    int ng = blockIdx.y;
    int ks = blockIdx.x * 8 + (threadIdx.x >> 5);
    int sl = threadIdx.x & 31;
    int kb = sl >> 3, n = sl & 7;
    int j = 8 * ng + n;
    int k0 = ks * 32 + kb * 8;
    const float* src = Wout + (size_t)j * 1024 + k0;

    union { short8_t v; unsigned short u[8]; } hi, lo;
#pragma unroll
    for (int e = 0; e < 8; ++e) {
        float v = src[e];
        hi.u[e] = f2bf(v);
        lo.u[e] = f2bf(v - bf2f(hi.u[e]));
    }
    size_t o = (((size_t)ng * 32 + ks) * 32 + sl) * 8;
    *(short8_t*)(POh + o) = hi.v;
    *(short8_t*)(POl + o) = lo.v;
}

// ---------------------------------------------------------------------------
// trans_h0f: h0[b][k] -> A-fragment layout [copy][mt][ks][lane][8] bf16 hi/lo
// ---------------------------------------------------------------------------
__global__ __launch_bounds__(256) void trans_h0f(
    const float* __restrict__ h0, unsigned short* __restrict__ hA)
{
    int id = blockIdx.x * 256 + threadIdx.x;   // [0, 16384)
    int lane = id & 63;
    int ks = (id >> 6) & 31;
    int mt = (id >> 11) & 3;
    int copy = id >> 13;
    int b = mt * 16 + (lane & 15);
    int k = ks * 32 + (lane >> 4) * 8;
    const float* src = h0 + (size_t)b * 1024 + k;

    union { short8_t v; unsigned short u[8]; } o;
#pragma unroll
    for (int e = 0; e < 8; ++e) {
        float v = src[e];
        unsigned short hb = f2bf(v);
        o.u[e] = (copy == 0) ? hb : f2bf(v - bf2f(hb));
    }
    *(short8_t*)(hA + (size_t)id * 8) = o.v;
}

// ---------------------------------------------------------------------------
// xproj bf16 MFMA GEMM; epilogue scatters to xpf[t][ng(128)][b][jj(8)][g(4)].
// ---------------------------------------------------------------------------
__global__ __launch_bounds__(256) void xproj_mfma(
    const float* __restrict__ X,
    const float* __restrict__ W0, const float* __restrict__ W1,
    const float* __restrict__ W2, const float* __restrict__ W3,
    unsigned short* __restrict__ xpf)
{
    __shared__ short8_t As[4 * 128];
    __shared__ short8_t Bs[4 * 128];

    const int bm = blockIdx.x;
    const int bn = blockIdx.y;
    const float* W = (bn < 8) ? W0 : (bn < 16) ? W1 : (bn < 24) ? W2 : W3;
    const int jbase = (bn & 7) * 128;
    const int m0 = bm * 128;

    const int tid  = threadIdx.x;
    const int lane = tid & 63;
    const int wave = tid >> 6;
    const int wm = wave >> 1, wn = wave & 1;
    const int q  = lane >> 4;
    const int lr = lane & 15;

    f32x4 acc[4][4];
#pragma unroll
    for (int i = 0; i < 4; ++i)
#pragma unroll
        for (int j = 0; j < 4; ++j) acc[i][j] = (f32x4){0.f, 0.f, 0.f, 0.f};

    for (int k0 = 0; k0 < 1024; k0 += 32) {
#pragma unroll
        for (int ss = 0; ss < 2; ++ss) {
            int s  = tid + ss * 256;
            int kg = s & 3, r = s >> 2;
            const float* xa = X + (size_t)(m0 + r) * 1024 + k0 + kg * 8;
            const float* wb = W + (size_t)(jbase + r) * 1024 + k0 + kg * 8;
            float4 a0 = *(const float4*)(xa);
            float4 a1 = *(const float4*)(xa + 4);
            float4 b0 = *(const float4*)(wb);
            float4 b1 = *(const float4*)(wb + 4);
            union { short8_t v; unsigned short u[8]; } ua, ub;
            float af[8] = {a0.x,a0.y,a0.z,a0.w,a1.x,a1.y,a1.z,a1.w};
            float bf[8] = {b0.x,b0.y,b0.z,b0.w,b1.x,b1.y,b1.z,b1.w};
#pragma unroll
            for (int e = 0; e < 8; ++e) {
                ua.u[e] = f2bf(af[e]);
                ub.u[e] = f2bf(bf[e]);
            }
            As[kg * 128 + r] = ua.v;
            Bs[kg * 128 + r] = ub.v;
        }
        __syncthreads();

        short8_t a[4], b[4];
#pragma unroll
        for (int mi = 0; mi < 4; ++mi)
            a[mi] = As[q * 128 + wm * 64 + mi * 16 + lr];
#pragma unroll
        for (int nj = 0; nj < 4; ++nj)
            b[nj] = Bs[q * 128 + wn * 64 + nj * 16 + lr];
#pragma unroll
        for (int mi = 0; mi < 4; ++mi)
#pragma unroll
            for (int nj = 0; nj < 4; ++nj)
                acc[mi][nj] = __builtin_amdgcn_mfma_f32_16x16x32_bf16(
                    a[mi], b[nj], acc[mi][nj], 0, 0, 0);
        __syncthreads();
    }

#pragma unroll
    for (int mi = 0; mi < 4; ++mi)
#pragma unroll
        for (int nj = 0; nj < 4; ++nj)
#pragma unroll
            for (int r = 0; r < 4; ++r) {
                int m = m0 + wm * 64 + mi * 16 + q * 4 + r;
                int n = bn * 128 + wn * 64 + nj * 16 + lr;
                int tt = m >> 6, bb = m & 63;
                int g = n >> 10, jc = n & 1023;
                xpf[(((size_t)tt * NBLK + (jc >> 3)) * 64 + bb) * 32 + (jc & 7) * 4 + g]
                    = f2bf(acc[mi][nj][r]);
            }
}

// ---------------------------------------------------------------------------
// Persistent MFMA LSTM loop, 128 blocks (halved L3 broadcast), striped
// barrier (16 stripes x 8 + master + 16 replicated flag lines).
// Block ng owns j in [8ng, 8ng+8): 32 gate cols (2 n-tiles) + 8 out cols.
// ---------------------------------------------------------------------------
__global__ __launch_bounds__(512, 1) void lstm_loop6(
    const unsigned short* __restrict__ xpf,
    const unsigned short* __restrict__ PGh, const unsigned short* __restrict__ PGl,
    const unsigned short* __restrict__ POh, const unsigned short* __restrict__ POl,
    const float* __restrict__ c0,
    unsigned short* __restrict__ hA, unsigned short* __restrict__ hB,
    float* __restrict__ out,
    unsigned* __restrict__ bar)
{
    __shared__ f32x4 red[8][12][64];    // [wave][mt*3+nc][lane]  96 KB
    __shared__ f32x4 redF[12][64];      //                        12 KB
    __shared__ unsigned short hsc[64 * 2 * 8];  // [b][cp][jj]     2 KB

    const int tid  = threadIdx.x;
    const int lane = tid & 63;
    const int kq   = tid >> 6;
    const int ng   = blockIdx.x;        // 0..127

    // ---- persistent B fragments in registers ----
    short8_t bgh[2][4], bgl[2][4], boh[4], bol[4];
#pragma unroll
    for (int i = 0; i < 4; ++i) {
        int ks = 4 * kq + i;
#pragma unroll
        for (int nt = 0; nt < 2; ++nt) {
            size_t og = (((size_t)(ng * 2 + nt) * 32 + ks) * 64 + lane) * 8;
            bgh[nt][i] = *(const short8_t*)(PGh + og);
            bgl[nt][i] = *(const short8_t*)(PGl + og);
        }
        short8_t zh = {0,0,0,0,0,0,0,0};
        short8_t zl = {0,0,0,0,0,0,0,0};
        if ((lane & 15) < 8) {
            size_t oo = (((size_t)ng * 32 + ks) * 32 + (lane >> 4) * 8 + (lane & 7)) * 8;
            zh = *(const short8_t*)(POh + oo);
            zl = *(const short8_t*)(POl + oo);
        }
        boh[i] = zh; bol[i] = zl;
    }

    // combine identity: all 512 threads, b = tid>>3, jj = tid&7
    const int cb = tid >> 3, cjj = tid & 7;
    float c_reg = c0[(size_t)cb * 1024 + 8 * ng + cjj];
    ushort4_t xq = *(const ushort4_t*)(xpf + ((size_t)ng * 64 + cb) * 32 + cjj * 4);

    // h-store address pieces: j-range [8ng,8ng+8) = one full 8-elem group
    const int ks2  = ng >> 2;
    const int l2hi = (ng & 3) << 4;

#pragma unroll 1
    for (int t = 0; t <= T_STEPS; ++t) {
        const unsigned short* hc = (t & 1) ? hB : hA;
        unsigned short*       hn = (t & 1) ? hA : hB;

        f32x4 acc[4][3];
#pragma unroll
        for (int mt = 0; mt < 4; ++mt)
#pragma unroll
            for (int nc = 0; nc < 3; ++nc)
                acc[mt][nc] = (f32x4){0.f, 0.f, 0.f, 0.f};

#pragma unroll
        for (int i = 0; i < 4; ++i) {
            const int ks = 4 * kq + i;
            short8_t ah[4], al[4];
#pragma unroll
            for (int mt = 0; mt < 4; ++mt) {
                int off = ((mt * 32 + ks) * 64 + lane) * 8;
                union { short8_t v; unsigned long long q[2]; } uh, ul;
                const unsigned long long* ph = (const unsigned long long*)(hc + off);
                const unsigned long long* pl = (const unsigned long long*)(hc + 65536 + off);
                uh.q[0] = __hip_atomic_load(ph,     __ATOMIC_RELAXED, __HIP_MEMORY_SCOPE_SYSTEM);
                uh.q[1] = __hip_atomic_load(ph + 1, __ATOMIC_RELAXED, __HIP_MEMORY_SCOPE_SYSTEM);
                ul.q[0] = __hip_atomic_load(pl,     __ATOMIC_RELAXED, __HIP_MEMORY_SCOPE_SYSTEM);
                ul.q[1] = __hip_atomic_load(pl + 1, __ATOMIC_RELAXED, __HIP_MEMORY_SCOPE_SYSTEM);
                ah[mt] = uh.v;
                al[mt] = ul.v;
            }
#pragma unroll
            for (int mt = 0; mt < 4; ++mt) {
                acc[mt][0] = __builtin_amdgcn_mfma_f32_16x16x32_bf16(ah[mt], bgh[0][i], acc[mt][0], 0,0,0);
                acc[mt][1] = __builtin_amdgcn_mfma_f32_16x16x32_bf16(ah[mt], bgh[1][i], acc[mt][1], 0,0,0);
                acc[mt][2] = __builtin_amdgcn_mfma_f32_16x16x32_bf16(ah[mt], boh[i],    acc[mt][2], 0,0,0);
                acc[mt][0] = __builtin_amdgcn_mfma_f32_16x16x32_bf16(al[mt], bgh[0][i], acc[mt][0], 0,0,0);
                acc[mt][1] = __builtin_amdgcn_mfma_f32_16x16x32_bf16(al[mt], bgh[1][i], acc[mt][1], 0,0,0);
                acc[mt][2] = __builtin_amdgcn_mfma_f32_16x16x32_bf16(al[mt], boh[i],    acc[mt][2], 0,0,0);
                acc[mt][0] = __builtin_amdgcn_mfma_f32_16x16x32_bf16(ah[mt], bgl[0][i], acc[mt][0], 0,0,0);
                acc[mt][1] = __builtin_amdgcn_mfma_f32_16x16x32_bf16(ah[mt], bgl[1][i], acc[mt][1], 0,0,0);
                acc[mt][2] = __builtin_amdgcn_mfma_f32_16x16x32_bf16(ah[mt], bol[i],    acc[mt][2], 0,0,0);
            }
        }

        // ---- K-reduction across 8 waves (12 tiles) ----
#pragma unroll
        for (int mt = 0; mt < 4; ++mt)
#pragma unroll
            for (int nc = 0; nc < 3; ++nc)
                red[kq][mt * 3 + nc][lane] = acc[mt][nc];
        __syncthreads();
        {
            f32x4 s = red[0][kq][lane];
#pragma unroll
            for (int q = 1; q < 8; ++q) s += red[q][kq][lane];
            redF[kq][lane] = s;
        }
        if (kq < 4) {
            const int tl = 8 + kq;
            f32x4 s = red[0][tl][lane];
#pragma unroll
            for (int q = 1; q < 8; ++q) s += red[q][tl][lane];
            redF[tl][lane] = s;
        }
        __syncthreads();

        // ---- combine (all 512 threads): gates -> c,h ; out[t-1] ----
        {
            const int mt = cb >> 4;
            const int lnb = (cb & 12) << 2;
            const int rg = cb & 3;
            float ov = redF[mt * 3 + 2][lnb | cjj][rg];
            if (t > 0)
                out[(size_t)(t - 1) * 65536 + cb * 1024 + 8 * ng + cjj] = ov;
            if (t < T_STEPS) {
                const int nt = cjj >> 2;
                float pre0 = redF[mt * 3 + nt][lnb | (0  + (cjj & 3))][rg] + bf2f(xq[0]);
                float pre1 = redF[mt * 3 + nt][lnb | (4  + (cjj & 3))][rg] + bf2f(xq[1]);
                float pre2 = redF[mt * 3 + nt][lnb | (8  + (cjj & 3))][rg] + bf2f(xq[2]);
                float pre3 = redF[mt * 3 + nt][lnb | (12 + (cjj & 3))][rg] + bf2f(xq[3]);
                float gi = 1.f / (1.f + expf(-pre0));
                float gf = 1.f / (1.f + expf(-pre1));
                float go = 1.f / (1.f + expf(-pre2));
                float cn = gf * c_reg + gi * tanhf(pre3);
                c_reg = cn;
                float hv = go * tanhf(cn);
                unsigned short hhi = f2bf(hv);
                unsigned short hlo = f2bf(hv - bf2f(hhi));
                hsc[(cb * 2 + 0) * 8 + cjj] = hhi;
                hsc[(cb * 2 + 1) * 8 + cjj] = hlo;
                if (t + 1 < T_STEPS)
                    xq = *(const ushort4_t*)(xpf +
                        (((size_t)(t + 1) * NBLK + ng) * 64 + cb) * 32 + cjj * 4);
            }
        }
        __syncthreads();

        // ---- h (bf16 hi/lo) 16B-per-thread bypass stores ----
        if (tid < 128 && t < T_STEPS) {
            int b = tid >> 1, cp = tid & 1;
            union { short8_t v; unsigned long long q[2]; } u;
            u.v = *(const short8_t*)&hsc[(b * 2 + cp) * 8];
            int elem = (((cp * 4 + (b >> 4)) * 32 + ks2) * 64 + ((b & 15) | l2hi)) * 8;
            __hip_atomic_store((unsigned long long*)(hn + elem),     u.q[0],
                               __ATOMIC_RELAXED, __HIP_MEMORY_SCOPE_SYSTEM);
            __hip_atomic_store((unsigned long long*)(hn + elem + 4), u.q[1],
                               __ATOMIC_RELAXED, __HIP_MEMORY_SCOPE_SYSTEM);
        }

        // ---- striped grid barrier: relaxed SYSTEM, no cache invalidates ----
        if (t < T_STEPS) {
            __syncthreads();
            if (tid == 0) {
                asm volatile("s_waitcnt vmcnt(0)" ::: "memory");
                const unsigned tgt = (unsigned)(t + 1);
                unsigned* scnt = bar + (ng >> 3) * 32;            // 16 stripes
                unsigned old = __hip_atomic_fetch_add(scnt, 1u,
                                   __ATOMIC_RELAXED, __HIP_MEMORY_SCOPE_SYSTEM);
                if (old == 8u * tgt - 1u) {
                    unsigned om = __hip_atomic_fetch_add(bar + 512, 1u,
                                   __ATOMIC_RELAXED, __HIP_MEMORY_SCOPE_SYSTEM);
                    if (om == 16u * tgt - 1u) {
#pragma unroll
                        for (int f = 0; f < 16; ++f)
                            __hip_atomic_store(bar + 576 + f * 32, tgt,
                                   __ATOMIC_RELAXED, __HIP_MEMORY_SCOPE_SYSTEM);
                    }
                }
                while (__hip_atomic_load(bar + 576 + (ng & 15) * 32,
                           __ATOMIC_RELAXED, __HIP_MEMORY_SCOPE_SYSTEM) < tgt)
                    __builtin_amdgcn_s_sleep(2);
            }
            __syncthreads();
        }
    }
}

// ---------------------------------------------------------------------------
extern "C" void kernel_launch(void* const* d_in, const int* in_sizes, int n_in,
                              void* d_out, int out_size, void* d_ws, size_t ws_size,
                              hipStream_t stream)
{
    const float* x    = (const float*)d_in[0];
    const float* h0   = (const float*)d_in[1];
    const float* c0   = (const float*)d_in[2];
    const float* Wxi  = (const float*)d_in[3];
    const float* Wxf  = (const float*)d_in[4];
    const float* Wxo  = (const float*)d_in[5];
    const float* Wxc  = (const float*)d_in[6];
    const float* Whi  = (const float*)d_in[7];
    const float* Whf  = (const float*)d_in[8];
    const float* Who  = (const float*)d_in[9];
    const float* Whc  = (const float*)d_in[10];
    const float* Wout = (const float*)d_in[11];
    float* out = (float*)d_out;

    const size_t PG_B  = (size_t)NBLK * 2 * 32 * 64 * 8 * 2;   //  8,388,608 each
    const size_t PO_B  = (size_t)NBLK * 32 * 32 * 8 * 2;       //  2,097,152 each
    const size_t HF_B  = (size_t)2 * 4 * 32 * 64 * 8 * 2;      //    262,144 each
    const size_t BAR_B = 8192;
    const size_t XPF_B = (size_t)T_STEPS * NBLK * 64 * 32 * 2; // 134,217,728

    char* ws = (char*)d_ws;
    unsigned short* PGh = (unsigned short*)ws;  ws += PG_B;
    unsigned short* PGl = (unsigned short*)ws;  ws += PG_B;
    unsigned short* POh = (unsigned short*)ws;  ws += PO_B;
    unsigned short* POl = (unsigned short*)ws;  ws += PO_B;
    unsigned short* hA  = (unsigned short*)ws;  ws += HF_B;
    unsigned short* hB  = (unsigned short*)ws;  ws += HF_B;
    unsigned*       bar = (unsigned*)ws;        ws += BAR_B;
    unsigned short* xpf = (unsigned short*)ws;  ws += XPF_B;

    hipMemsetAsync(bar, 0, BAR_B, stream);
    pack_gate<<<dim3(16, NBLK), 256, 0, stream>>>(Whi, Whf, Who, Whc, PGh, PGl);
    pack_out<<<dim3(4, NBLK), 256, 0, stream>>>(Wout, POh, POl);
    trans_h0f<<<dim3(64), 256, 0, stream>>>(h0, hA);
    xproj_mfma<<<dim3(128, 32), 256, 0, stream>>>(x, Wxi, Wxf, Wxo, Wxc, xpf);

    lstm_loop6<<<dim3(NBLK), dim3(512), 0, stream>>>(
        xpf, PGh, PGl, POh, POl, c0, hA, hB, out, bar);
}